// Round 1
// baseline (651.762 us; speedup 1.0000x reference)
//
#include <hip/hip_runtime.h>
#include <math.h>

#define BATCH 16
#define TA 2048
#define TV 1024
#define TT 1536
#define DIM 256
#define FD 512

typedef unsigned short u16;
typedef unsigned int u32;
typedef short bf16x8 __attribute__((ext_vector_type(8)));
typedef float f32x4 __attribute__((ext_vector_type(4)));

__device__ __forceinline__ float bf2f(u16 u) {
  union { u32 i; float f; } v; v.i = ((u32)u) << 16; return v.f;
}
__device__ __forceinline__ u16 f2bf(float f) {
  union { float f; u32 i; } v; v.f = f;
  return (u16)((v.i + 0x7fffu + ((v.i >> 16) & 1u)) >> 16);  // RNE
}
__device__ __forceinline__ float gelu_f(float x) {
  return 0.5f * x * (1.0f + erff(x * 0.70710678118654752440f));
}
// async global->LDS, 16B per lane. LDS dest = wave-uniform base + lane*16.
__device__ __forceinline__ void async16(const u16* g, u16* l) {
  __builtin_amdgcn_global_load_lds((const __attribute__((address_space(1))) void*)g,
                                   (__attribute__((address_space(3))) void*)l, 16, 0, 0);
}

// ---------------- weight prep: fp32 -> bf16, conv weights to [tap][o][c] ----
__global__ __launch_bounds__(256) void k_prep(
    const float* __restrict__ a3w, const float* __restrict__ a5w,
    const float* __restrict__ v3w, const float* __restrict__ v5w,
    const float* __restrict__ pw,
    u16* __restrict__ w3a, u16* __restrict__ w5a,
    u16* __restrict__ w3v, u16* __restrict__ w5v, u16* __restrict__ wp) {
  int idx = blockIdx.x * 256 + threadIdx.x;
  if (idx < 98304) {                       // a3: [128][256][3] -> [3][128][256]
    int k = idx >> 15, o = (idx >> 8) & 127, c = idx & 255;
    w3a[idx] = f2bf(a3w[(o * 256 + c) * 3 + k]);
  } else if (idx < 262144) {               // a5
    int t = idx - 98304;
    int k = t >> 15, o = (t >> 8) & 127, c = t & 255;
    w5a[t] = f2bf(a5w[(o * 256 + c) * 5 + k]);
  } else if (idx < 360448) {               // v3
    int t = idx - 262144;
    int k = t >> 15, o = (t >> 8) & 127, c = t & 255;
    w3v[t] = f2bf(v3w[(o * 256 + c) * 3 + k]);
  } else if (idx < 524288) {               // v5
    int t = idx - 360448;
    int k = t >> 15, o = (t >> 8) & 127, c = t & 255;
    w5v[t] = f2bf(v5w[(o * 256 + c) * 5 + k]);
  } else if (idx < 786432) {               // proj [512][512] straight copy
    int t = idx - 524288;
    wp[t] = f2bf(pw[t]);
  }
}

// ---------------- linear interp to T=1536, output bf16 [B][T][256] ----------
__global__ __launch_bounds__(256) void k_interp(const float* __restrict__ in,
                                                u16* __restrict__ out,
                                                int t_in, float scale) {
  int b = blockIdx.y;
  int i = blockIdx.x * 256 + threadIdx.x;   // [0, TT*32)
  int t = i >> 5, dg = i & 31;              // dg: group of 8 dims
  float src = ((float)t + 0.5f) * scale - 0.5f;
  src = fmaxf(src, 0.0f);
  int i0 = (int)floorf(src);
  if (i0 > t_in - 1) i0 = t_in - 1;
  int i1 = i0 + 1; if (i1 > t_in - 1) i1 = t_in - 1;
  float w = src - (float)i0;
  float om = 1.0f - w;
  const float4* p0 = (const float4*)(in + ((size_t)(b * t_in + i0)) * DIM + dg * 8);
  const float4* p1 = (const float4*)(in + ((size_t)(b * t_in + i1)) * DIM + dg * 8);
  float4 x0a = p0[0], x0b = p0[1], x1a = p1[0], x1b = p1[1];
  u16 r[8];
  r[0] = f2bf(x0a.x * om + x1a.x * w); r[1] = f2bf(x0a.y * om + x1a.y * w);
  r[2] = f2bf(x0a.z * om + x1a.z * w); r[3] = f2bf(x0a.w * om + x1a.w * w);
  r[4] = f2bf(x0b.x * om + x1b.x * w); r[5] = f2bf(x0b.y * om + x1b.y * w);
  r[6] = f2bf(x0b.z * om + x1b.z * w); r[7] = f2bf(x0b.w * om + x1b.w * w);
  u32 w0 = (u32)r[0] | ((u32)r[1] << 16), w1 = (u32)r[2] | ((u32)r[3] << 16);
  u32 w2 = (u32)r[4] | ((u32)r[5] << 16), w3 = (u32)r[6] | ((u32)r[7] << 16);
  *(uint4*)(out + ((size_t)(b * TT + t)) * DIM + dg * 8) = make_uint4(w0, w1, w2, w3);
}

// ---------------- conv(k=3 | k=5) + GELU + row-norm ------------------------
// in:  bf16 interp [B][T][256]
// out: outN [B][T][256] normalized (K-contig, glds-ready for sim GEMM)
//      outT [B][256][T] unnormalized transposed (glds-ready PV B-operand)
__global__ __launch_bounds__(256) void k_conv(
    const u16* __restrict__ xin,
    const u16* __restrict__ w3, const u16* __restrict__ w5,
    const float* __restrict__ b3, const float* __restrict__ b5,
    u16* __restrict__ outN, u16* __restrict__ outT) {
  __shared__ u16 xs[20 * 264];         // rows t0-2..t0+17, stride 264 (pad 8)
  __shared__ u16 tb[256 * 18];         // transpose buffer [d][16+pad2]
  __shared__ float red[4][16];
  __shared__ float rnorm[16];
  int b = blockIdx.y, t0 = blockIdx.x * 16;
  int tid = threadIdx.x, wave = tid >> 6, lane = tid & 63;
  int col = lane & 15, quad = lane >> 4;

  // stage 20 input rows (zeros outside [0,T))
  for (int idx = tid; idx < 20 * 128; idx += 256) {
    int r = idx >> 7, cp = idx & 127;
    int t = t0 + r - 2;
    u32 val = 0;
    if (t >= 0 && t < TT) val = *(const u32*)(xin + ((size_t)(b * TT + t)) * DIM + cp * 2);
    *(u32*)(xs + r * 264 + cp * 2) = val;
  }
  __syncthreads();

  bool is5 = wave >= 2;
  int taps = is5 ? 5 : 3;
  const u16* W = is5 ? w5 : w3;
  const float* bp = is5 ? b5 : b3;
  int olb = (wave & 1) * 64;     // local o-base within the conv's 128 channels
  int obase = wave * 64;         // global channel base (0..255)

  f32x4 acc[4];
  f32x4 zz = {0.f, 0.f, 0.f, 0.f};
  acc[0] = zz; acc[1] = zz; acc[2] = zz; acc[3] = zz;

  for (int tap = 0; tap < taps; tap++) {
    int roff = is5 ? tap : tap + 1;
    for (int ch = 0; ch < 8; ch++) {
      bf16x8 af = *(const bf16x8*)(xs + (roff + col) * 264 + ch * 32 + quad * 8);
      const u16* wb = W + ((size_t)tap * 128 + olb) * 256 + ch * 32 + quad * 8;
#pragma unroll
      for (int nt = 0; nt < 4; nt++) {
        bf16x8 bfr = *(const bf16x8*)(wb + (nt * 16 + col) * 256);
        acc[nt] = __builtin_amdgcn_mfma_f32_16x16x32_bf16(af, bfr, acc[nt], 0, 0, 0);
      }
    }
  }
  // epilogue: bias + gelu + sumsq over 256 channels per time-row
  float gv[4][4];
  float ss[4] = {0.f, 0.f, 0.f, 0.f};
#pragma unroll
  for (int nt = 0; nt < 4; nt++) {
    float bia = bp[olb + nt * 16 + col];
#pragma unroll
    for (int r = 0; r < 4; r++) {
      float x = acc[nt][r] + bia;
      float g = gelu_f(x);
      gv[nt][r] = g;
      ss[r] += g * g;
    }
  }
#pragma unroll
  for (int r = 0; r < 4; r++) {
#pragma unroll
    for (int m = 1; m < 16; m <<= 1) ss[r] += __shfl_xor(ss[r], m, 64);
  }
  if ((lane & 15) == 0) {
#pragma unroll
    for (int r = 0; r < 4; r++) red[wave][quad * 4 + r] = ss[r];
  }
  __syncthreads();
  if (tid < 16) {
    float tot = red[0][tid] + red[1][tid] + red[2][tid] + red[3][tid];
    rnorm[tid] = 1.0f / fmaxf(sqrtf(tot), 1e-12f);
  }
  __syncthreads();
#pragma unroll
  for (int nt = 0; nt < 4; nt++) {
    int o = obase + nt * 16 + col;
#pragma unroll
    for (int r = 0; r < 4; r++) {
      int row = quad * 4 + r;
      tb[o * 18 + row] = f2bf(gv[nt][r]);
      outN[((size_t)(b * TT + t0 + row)) * DIM + o] = f2bf(gv[nt][r] * rnorm[row]);
    }
  }
  __syncthreads();
  {
    int d = tid;
    u32 px[8];
#pragma unroll
    for (int i = 0; i < 8; i++) px[i] = *(const u32*)(tb + d * 18 + i * 2);
    uint4* dst = (uint4*)(outT + ((size_t)(b * 256 + d)) * TT + t0);
    dst[0] = make_uint4(px[0], px[1], px[2], px[3]);
    dst[1] = make_uint4(px[4], px[5], px[6], px[7]);
  }
}

// ---------------- sim = aN . vN^T  (gemm_bt, 128x128 tile, BK=32) ----------
__global__ __launch_bounds__(256) void k_sim(const u16* __restrict__ A,
                                             const u16* __restrict__ Bm,
                                             u16* __restrict__ Cc) {
  __shared__ u16 As[128 * 32], Bs[128 * 32];
  int b = blockIdx.z, m0 = blockIdx.y * 128, n0 = blockIdx.x * 128;
  int tid = threadIdx.x, wave = tid >> 6, lane = tid & 63;
  int col = lane & 15, quad = lane >> 4;
  int wm = (wave >> 1) * 64, wn = (wave & 1) * 64;
  int lrow = lane >> 2, lcol = (lane & 3) * 8;
  const u16* Ab = A + ((size_t)(b * TT + m0)) * DIM;
  const u16* Bb = Bm + ((size_t)(b * TT + n0)) * DIM;
  f32x4 acc[4][4];
  f32x4 zz = {0.f, 0.f, 0.f, 0.f};
#pragma unroll
  for (int i = 0; i < 4; i++)
#pragma unroll
    for (int j = 0; j < 4; j++) acc[i][j] = zz;

  for (int kt = 0; kt < 8; kt++) {
    int k0 = kt * 32;
    if (kt) __syncthreads();
#pragma unroll
    for (int i = 0; i < 2; i++) {
      int rb = wave * 32 + i * 16;
      async16(Ab + ((size_t)(rb + lrow)) * DIM + k0 + lcol, As + rb * 32);
      async16(Bb + ((size_t)(rb + lrow)) * DIM + k0 + lcol, Bs + rb * 32);
    }
    __syncthreads();
    bf16x8 af[4], bfr[4];
#pragma unroll
    for (int mt = 0; mt < 4; mt++) af[mt] = *(const bf16x8*)(As + (wm + mt * 16 + col) * 32 + quad * 8);
#pragma unroll
    for (int nt = 0; nt < 4; nt++) bfr[nt] = *(const bf16x8*)(Bs + (wn + nt * 16 + col) * 32 + quad * 8);
#pragma unroll
    for (int mt = 0; mt < 4; mt++)
#pragma unroll
      for (int nt = 0; nt < 4; nt++)
        acc[mt][nt] = __builtin_amdgcn_mfma_f32_16x16x32_bf16(af[mt], bfr[nt], acc[mt][nt], 0, 0, 0);
  }
#pragma unroll
  for (int mt = 0; mt < 4; mt++)
#pragma unroll
    for (int nt = 0; nt < 4; nt++)
#pragma unroll
      for (int r = 0; r < 4; r++) {
        int row = m0 + wm + mt * 16 + quad * 4 + r;
        int cc = n0 + wn + nt * 16 + col;
        Cc[((size_t)b * TT + row) * TT + cc] = f2bf(acc[mt][nt][r]);
      }
}

// ---------------- row stats: max & sumexp over s (axis -1) -----------------
__global__ __launch_bounds__(256) void k_rowstats(const u16* __restrict__ sim,
                                                  float* __restrict__ rmax,
                                                  float* __restrict__ rsum) {
  int wave = threadIdx.x >> 6, lane = threadIdx.x & 63;
  int row = blockIdx.x * 4 + wave;          // [0, B*T)
  const u32* p = (const u32*)(sim + (size_t)row * TT);
  float xs[24];
  float m = -__builtin_inff();
#pragma unroll
  for (int i = 0; i < 12; i++) {
    u32 v = p[lane + 64 * i];
    float x0 = bf2f((u16)(v & 0xffffu));
    float x1 = bf2f((u16)(v >> 16));
    xs[2 * i] = x0; xs[2 * i + 1] = x1;
    m = fmaxf(m, fmaxf(x0, x1));
  }
#pragma unroll
  for (int s = 1; s < 64; s <<= 1) m = fmaxf(m, __shfl_xor(m, s, 64));
  float l = 0.f;
#pragma unroll
  for (int i = 0; i < 24; i++) l += __expf(xs[i] - m);
#pragma unroll
  for (int s = 1; s < 64; s <<= 1) l += __shfl_xor(l, s, 64);
  if (lane == 0) { rmax[row] = m; rsum[row] = l; }
}

// ---------------- col stats: max & sumexp over t (axis 1) ------------------
__global__ __launch_bounds__(256) void k_colstats(const u16* __restrict__ sim,
                                                  float* __restrict__ cmax,
                                                  float* __restrict__ csum) {
  int b = blockIdx.y, j = blockIdx.x * 256 + threadIdx.x;
  const u16* p = sim + (size_t)b * TT * TT + j;
  float m[4] = {-__builtin_inff(), -__builtin_inff(), -__builtin_inff(), -__builtin_inff()};
  float l[4] = {0.f, 0.f, 0.f, 0.f};
  for (int i = 0; i < TT; i += 4) {
#pragma unroll
    for (int u = 0; u < 4; u++) {
      float x = bf2f(p[(size_t)(i + u) * TT]);
      if (x > m[u]) { l[u] *= __expf(m[u] - x); m[u] = x; }
      l[u] += __expf(x - m[u]);
    }
  }
  float M = fmaxf(fmaxf(m[0], m[1]), fmaxf(m[2], m[3]));
  float L = l[0] * __expf(m[0] - M) + l[1] * __expf(m[1] - M) +
            l[2] * __expf(m[2] - M) + l[3] * __expf(m[3] - M);
  cmax[b * TT + j] = M;
  csum[b * TT + j] = L;
}

// ---------------- PV: fused[...] = itp + softmax(sim) @ values -------------
// TRANSA=0: A[m][k] = exp(sim[b][m0+m][k] - rmax[m]) (a_enh, row softmax)
// TRANSA=1: A[m][k] = exp(sim[b][k][m0+m] - cmax[m]) (v_enh, col softmax)
// B operand: xMT [B][256][T] (unnormalized transposed multi features)
// tile: 64(m) x 128(n), BK=32, 4 waves of 32x64
template <int TRANSA>
__global__ __launch_bounds__(256) void k_pv(
    const u16* __restrict__ sim, const u16* __restrict__ Bt,
    const float* __restrict__ stmax, const float* __restrict__ stsum,
    const u16* __restrict__ itp, u16* __restrict__ fused, int dstoff) {
  __shared__ u16 As[64 * 40];         // padded stride 40
  __shared__ u16 Bs[128 * 32];
  __shared__ float sMax[64], sSum[64];
  int b = blockIdx.z, m0 = blockIdx.y * 64, n0 = blockIdx.x * 128;
  int tid = threadIdx.x, wave = tid >> 6, lane = tid & 63;
  int col = lane & 15, quad = lane >> 4;
  int wm = (wave >> 1) * 32, wn = (wave & 1) * 64;
  int lrow = lane >> 2, lcol = (lane & 3) * 8;
  if (tid < 64) {
    sMax[tid] = stmax[b * TT + m0 + tid];
    sSum[tid] = stsum[b * TT + m0 + tid];
  }
  __syncthreads();
  const u16* Bb = Bt + ((size_t)b * 256 + n0) * TT;
  f32x4 acc[2][4];
  f32x4 zz = {0.f, 0.f, 0.f, 0.f};
#pragma unroll
  for (int i = 0; i < 2; i++)
#pragma unroll
    for (int j = 0; j < 4; j++) acc[i][j] = zz;

  for (int kt = 0; kt < 48; kt++) {
    int k0 = kt * 32;
    if (kt) __syncthreads();
#pragma unroll
    for (int i = 0; i < 2; i++) {
      int rb = wave * 32 + i * 16;
      async16(Bb + ((size_t)(rb + lrow)) * TT + k0 + lcol, Bs + rb * 32);
    }
    if (TRANSA == 0) {
      int row = tid >> 2, kp = (tid & 3) * 8;
      uint4 v = *(const uint4*)(sim + ((size_t)(b * TT + m0 + row)) * TT + k0 + kp);
      float mx = sMax[row];
      const u16* pv = (const u16*)&v;
      u32 w[4];
#pragma unroll
      for (int h = 0; h < 4; h++) {
        float e0 = __expf(bf2f(pv[2 * h]) - mx);
        float e1 = __expf(bf2f(pv[2 * h + 1]) - mx);
        w[h] = (u32)f2bf(e0) | ((u32)f2bf(e1) << 16);
      }
      *(uint4*)(As + row * 40 + kp) = make_uint4(w[0], w[1], w[2], w[3]);
    } else {
      int s_r = tid >> 3, tp = (tid & 7) * 8;
      uint4 v = *(const uint4*)(sim + ((size_t)(b * TT + k0 + s_r)) * TT + m0 + tp);
      const u16* pv = (const u16*)&v;
#pragma unroll
      for (int jx = 0; jx < 8; jx++) {
        int j = (jx + (lane & 7)) & 7;  // rotate to spread LDS banks
        float e = __expf(bf2f(pv[j]) - sMax[tp + j]);
        As[(tp + j) * 40 + s_r] = f2bf(e);
      }
    }
    __syncthreads();
    bf16x8 af[2], bfr[4];
#pragma unroll
    for (int mt = 0; mt < 2; mt++) af[mt] = *(const bf16x8*)(As + (wm + mt * 16 + col) * 40 + quad * 8);
#pragma unroll
    for (int nt = 0; nt < 4; nt++) bfr[nt] = *(const bf16x8*)(Bs + (wn + nt * 16 + col) * 32 + quad * 8);
#pragma unroll
    for (int mt = 0; mt < 2; mt++)
#pragma unroll
      for (int nt = 0; nt < 4; nt++)
        acc[mt][nt] = __builtin_amdgcn_mfma_f32_16x16x32_bf16(af[mt], bfr[nt], acc[mt][nt], 0, 0, 0);
  }
#pragma unroll
  for (int mt = 0; mt < 2; mt++)
#pragma unroll
    for (int nt = 0; nt < 4; nt++)
#pragma unroll
      for (int r = 0; r < 4; r++) {
        int row = wm + mt * 16 + quad * 4 + r;
        int t = m0 + row;
        int d = n0 + wn + nt * 16 + col;
        float val = acc[mt][nt][r] / sSum[row] + bf2f(itp[((size_t)(b * TT + t)) * DIM + d]);
        fused[((size_t)(b * TT + t)) * FD + dstoff + d] = f2bf(val);
      }
}

// ---------------- proj: out = gelu(fused @ Wp^T + b), fp32 out -------------
__global__ __launch_bounds__(256) void k_proj(const u16* __restrict__ Am,
                                              const u16* __restrict__ Bw,
                                              const float* __restrict__ bias,
                                              float* __restrict__ out) {
  __shared__ u16 As[128 * 32], Bs[128 * 32];
  int m0 = blockIdx.y * 128, n0 = blockIdx.x * 128;
  int tid = threadIdx.x, wave = tid >> 6, lane = tid & 63;
  int col = lane & 15, quad = lane >> 4;
  int wm = (wave >> 1) * 64, wn = (wave & 1) * 64;
  int lrow = lane >> 2, lcol = (lane & 3) * 8;
  const u16* Ab = Am + (size_t)m0 * FD;
  const u16* Bb = Bw + (size_t)n0 * FD;
  f32x4 acc[4][4];
  f32x4 zz = {0.f, 0.f, 0.f, 0.f};
#pragma unroll
  for (int i = 0; i < 4; i++)
#pragma unroll
    for (int j = 0; j < 4; j++) acc[i][j] = zz;

  for (int kt = 0; kt < 16; kt++) {
    int k0 = kt * 32;
    if (kt) __syncthreads();
#pragma unroll
    for (int i = 0; i < 2; i++) {
      int rb = wave * 32 + i * 16;
      async16(Ab + ((size_t)(rb + lrow)) * FD + k0 + lcol, As + rb * 32);
      async16(Bb + ((size_t)(rb + lrow)) * FD + k0 + lcol, Bs + rb * 32);
    }
    __syncthreads();
    bf16x8 af[4], bfr[4];
#pragma unroll
    for (int mt = 0; mt < 4; mt++) af[mt] = *(const bf16x8*)(As + (wm + mt * 16 + col) * 32 + quad * 8);
#pragma unroll
    for (int nt = 0; nt < 4; nt++) bfr[nt] = *(const bf16x8*)(Bs + (wn + nt * 16 + col) * 32 + quad * 8);
#pragma unroll
    for (int mt = 0; mt < 4; mt++)
#pragma unroll
      for (int nt = 0; nt < 4; nt++)
        acc[mt][nt] = __builtin_amdgcn_mfma_f32_16x16x32_bf16(af[mt], bfr[nt], acc[mt][nt], 0, 0, 0);
  }
#pragma unroll
  for (int nt = 0; nt < 4; nt++) {
    float bia = bias[n0 + wn + nt * 16 + col];
#pragma unroll
    for (int mt = 0; mt < 4; mt++)
#pragma unroll
      for (int r = 0; r < 4; r++) {
        int row = m0 + wm + mt * 16 + quad * 4 + r;
        int cc = n0 + wn + nt * 16 + col;
        out[(size_t)row * FD + cc] = gelu_f(acc[mt][nt][r] + bia);
      }
  }
}

extern "C" void kernel_launch(void* const* d_in, const int* in_sizes, int n_in,
                              void* d_out, int out_size, void* d_ws, size_t ws_size,
                              hipStream_t stream) {
  const float* audio = (const float*)d_in[0];
  const float* video = (const float*)d_in[1];
  const float* a3w = (const float*)d_in[2];
  const float* a3b = (const float*)d_in[3];
  const float* a5w = (const float*)d_in[4];
  const float* a5b = (const float*)d_in[5];
  const float* v3w = (const float*)d_in[6];
  const float* v3b = (const float*)d_in[7];
  const float* v5w = (const float*)d_in[8];
  const float* v5b = (const float*)d_in[9];
  const float* pw  = (const float*)d_in[10];
  const float* pb  = (const float*)d_in[11];
  float* out = (float*)d_out;

  char* ws = (char*)d_ws;
  size_t off = 0;
  auto alloc = [&](size_t bytes) {
    char* p = ws + off;
    off += (bytes + 255) & ~(size_t)255;
    return p;
  };
  size_t szItp = (size_t)BATCH * TT * DIM * 2;
  u16* a_itp = (u16*)alloc(szItp);
  u16* v_itp = (u16*)alloc(szItp);
  u16* aN  = (u16*)alloc(szItp);
  u16* vN  = (u16*)alloc(szItp);
  u16* aMT = (u16*)alloc(szItp);
  u16* vMT = (u16*)alloc(szItp);
  u16* sim = (u16*)alloc((size_t)BATCH * TT * TT * 2);
  float* rmax = (float*)alloc((size_t)BATCH * TT * 4);
  float* rsum = (float*)alloc((size_t)BATCH * TT * 4);
  float* cmax = (float*)alloc((size_t)BATCH * TT * 4);
  float* csum = (float*)alloc((size_t)BATCH * TT * 4);
  u16* fusedb = (u16*)alloc((size_t)BATCH * TT * FD * 2);
  u16* w3a = (u16*)alloc(3 * 128 * 256 * 2);
  u16* w5a = (u16*)alloc(5 * 128 * 256 * 2);
  u16* w3v = (u16*)alloc(3 * 128 * 256 * 2);
  u16* w5v = (u16*)alloc(5 * 128 * 256 * 2);
  u16* wp  = (u16*)alloc(512 * 512 * 2);

  k_prep<<<3072, 256, 0, stream>>>(a3w, a5w, v3w, v5w, pw, w3a, w5a, w3v, w5v, wp);
  k_interp<<<dim3(192, 16), 256, 0, stream>>>(audio, a_itp, TA, (float)((double)TA / TT));
  k_interp<<<dim3(192, 16), 256, 0, stream>>>(video, v_itp, TV, (float)((double)TV / TT));
  k_conv<<<dim3(96, 16), 256, 0, stream>>>(a_itp, w3a, w5a, a3b, a5b, aN, aMT);
  k_conv<<<dim3(96, 16), 256, 0, stream>>>(v_itp, w3v, w5v, v3b, v5b, vN, vMT);
  k_sim<<<dim3(12, 12, 16), 256, 0, stream>>>(aN, vN, sim);
  k_rowstats<<<6144, 256, 0, stream>>>(sim, rmax, rsum);
  k_colstats<<<dim3(6, 16), 256, 0, stream>>>(sim, cmax, csum);
  k_pv<0><<<dim3(2, 24, 16), 256, 0, stream>>>(sim, vMT, rmax, rsum, a_itp, fusedb, 0);
  k_pv<1><<<dim3(2, 24, 16), 256, 0, stream>>>(sim, aMT, cmax, csum, v_itp, fusedb, 256);
  k_proj<<<dim3(4, 192), 256, 0, stream>>>(fusedb, wp, pb, out);
}

// Round 2
// 556.660 us; speedup vs baseline: 1.1708x; 1.1708x over previous
//
#include <hip/hip_runtime.h>
#include <math.h>

#define BATCH 16
#define TA 2048
#define TV 1024
#define TT 1536
#define DIM 256
#define FD 512
#define NCH 12   // column-stats row chunks (1536/128)

typedef unsigned short u16;
typedef unsigned int u32;
typedef short bf16x8 __attribute__((ext_vector_type(8)));
typedef float f32x4 __attribute__((ext_vector_type(4)));

__device__ __forceinline__ float bf2f(u16 u) {
  union { u32 i; float f; } v; v.i = ((u32)u) << 16; return v.f;
}
__device__ __forceinline__ u16 f2bf(float f) {
  union { float f; u32 i; } v; v.f = f;
  return (u16)((v.i + 0x7fffu + ((v.i >> 16) & 1u)) >> 16);  // RNE
}
__device__ __forceinline__ float gelu_f(float x) {
  return 0.5f * x * (1.0f + erff(x * 0.70710678118654752440f));
}
// async global->LDS, 16B per lane. LDS dest = wave-uniform base + lane*16.
__device__ __forceinline__ void async16(const u16* g, u16* l) {
  __builtin_amdgcn_global_load_lds((const __attribute__((address_space(1))) void*)g,
                                   (__attribute__((address_space(3))) void*)l, 16, 0, 0);
}

// ---------------- weight prep: fp32 -> bf16, conv weights to [tap][o][c] ----
__global__ __launch_bounds__(256) void k_prep(
    const float* __restrict__ a3w, const float* __restrict__ a5w,
    const float* __restrict__ v3w, const float* __restrict__ v5w,
    const float* __restrict__ pw,
    u16* __restrict__ w3a, u16* __restrict__ w5a,
    u16* __restrict__ w3v, u16* __restrict__ w5v, u16* __restrict__ wp) {
  int idx = blockIdx.x * 256 + threadIdx.x;
  if (idx < 98304) {                       // a3: [128][256][3] -> [3][128][256]
    int k = idx >> 15, o = (idx >> 8) & 127, c = idx & 255;
    w3a[idx] = f2bf(a3w[(o * 256 + c) * 3 + k]);
  } else if (idx < 262144) {               // a5
    int t = idx - 98304;
    int k = t >> 15, o = (t >> 8) & 127, c = t & 255;
    w5a[t] = f2bf(a5w[(o * 256 + c) * 5 + k]);
  } else if (idx < 360448) {               // v3
    int t = idx - 262144;
    int k = t >> 15, o = (t >> 8) & 127, c = t & 255;
    w3v[t] = f2bf(v3w[(o * 256 + c) * 3 + k]);
  } else if (idx < 524288) {               // v5
    int t = idx - 360448;
    int k = t >> 15, o = (t >> 8) & 127, c = t & 255;
    w5v[t] = f2bf(v5w[(o * 256 + c) * 5 + k]);
  } else if (idx < 786432) {               // proj [512][512] straight copy
    int t = idx - 524288;
    wp[t] = f2bf(pw[t]);
  }
}

// ---------------- linear interp to T=1536, output bf16 [B][T][256] ----------
__global__ __launch_bounds__(256) void k_interp(const float* __restrict__ in,
                                                u16* __restrict__ out,
                                                int t_in, float scale) {
  int b = blockIdx.y;
  int i = blockIdx.x * 256 + threadIdx.x;   // [0, TT*32)
  int t = i >> 5, dg = i & 31;              // dg: group of 8 dims
  float src = ((float)t + 0.5f) * scale - 0.5f;
  src = fmaxf(src, 0.0f);
  int i0 = (int)floorf(src);
  if (i0 > t_in - 1) i0 = t_in - 1;
  int i1 = i0 + 1; if (i1 > t_in - 1) i1 = t_in - 1;
  float w = src - (float)i0;
  float om = 1.0f - w;
  const float4* p0 = (const float4*)(in + ((size_t)(b * t_in + i0)) * DIM + dg * 8);
  const float4* p1 = (const float4*)(in + ((size_t)(b * t_in + i1)) * DIM + dg * 8);
  float4 x0a = p0[0], x0b = p0[1], x1a = p1[0], x1b = p1[1];
  u16 r[8];
  r[0] = f2bf(x0a.x * om + x1a.x * w); r[1] = f2bf(x0a.y * om + x1a.y * w);
  r[2] = f2bf(x0a.z * om + x1a.z * w); r[3] = f2bf(x0a.w * om + x1a.w * w);
  r[4] = f2bf(x0b.x * om + x1b.x * w); r[5] = f2bf(x0b.y * om + x1b.y * w);
  r[6] = f2bf(x0b.z * om + x1b.z * w); r[7] = f2bf(x0b.w * om + x1b.w * w);
  u32 w0 = (u32)r[0] | ((u32)r[1] << 16), w1 = (u32)r[2] | ((u32)r[3] << 16);
  u32 w2 = (u32)r[4] | ((u32)r[5] << 16), w3 = (u32)r[6] | ((u32)r[7] << 16);
  *(uint4*)(out + ((size_t)(b * TT + t)) * DIM + dg * 8) = make_uint4(w0, w1, w2, w3);
}

// ---------------- conv(k=3 | k=5) + GELU + row-norm ------------------------
__global__ __launch_bounds__(256) void k_conv(
    const u16* __restrict__ xin,
    const u16* __restrict__ w3, const u16* __restrict__ w5,
    const float* __restrict__ b3, const float* __restrict__ b5,
    u16* __restrict__ outN, u16* __restrict__ outT) {
  __shared__ u16 xs[20 * 264];         // rows t0-2..t0+17, stride 264 (pad 8)
  __shared__ u16 tb[256 * 18];         // transpose buffer [d][16+pad2]
  __shared__ float red[4][16];
  __shared__ float rnorm[16];
  int b = blockIdx.y, t0 = blockIdx.x * 16;
  int tid = threadIdx.x, wave = tid >> 6, lane = tid & 63;
  int col = lane & 15, quad = lane >> 4;

  for (int idx = tid; idx < 20 * 128; idx += 256) {
    int r = idx >> 7, cp = idx & 127;
    int t = t0 + r - 2;
    u32 val = 0;
    if (t >= 0 && t < TT) val = *(const u32*)(xin + ((size_t)(b * TT + t)) * DIM + cp * 2);
    *(u32*)(xs + r * 264 + cp * 2) = val;
  }
  __syncthreads();

  bool is5 = wave >= 2;
  int taps = is5 ? 5 : 3;
  const u16* W = is5 ? w5 : w3;
  const float* bp = is5 ? b5 : b3;
  int olb = (wave & 1) * 64;
  int obase = wave * 64;

  f32x4 acc[4];
  f32x4 zz = {0.f, 0.f, 0.f, 0.f};
  acc[0] = zz; acc[1] = zz; acc[2] = zz; acc[3] = zz;

  for (int tap = 0; tap < taps; tap++) {
    int roff = is5 ? tap : tap + 1;
    for (int ch = 0; ch < 8; ch++) {
      bf16x8 af = *(const bf16x8*)(xs + (roff + col) * 264 + ch * 32 + quad * 8);
      const u16* wb = W + ((size_t)tap * 128 + olb) * 256 + ch * 32 + quad * 8;
#pragma unroll
      for (int nt = 0; nt < 4; nt++) {
        bf16x8 bfr = *(const bf16x8*)(wb + (nt * 16 + col) * 256);
        acc[nt] = __builtin_amdgcn_mfma_f32_16x16x32_bf16(af, bfr, acc[nt], 0, 0, 0);
      }
    }
  }
  float gv[4][4];
  float ss[4] = {0.f, 0.f, 0.f, 0.f};
#pragma unroll
  for (int nt = 0; nt < 4; nt++) {
    float bia = bp[olb + nt * 16 + col];
#pragma unroll
    for (int r = 0; r < 4; r++) {
      float x = acc[nt][r] + bia;
      float g = gelu_f(x);
      gv[nt][r] = g;
      ss[r] += g * g;
    }
  }
#pragma unroll
  for (int r = 0; r < 4; r++) {
#pragma unroll
    for (int m = 1; m < 16; m <<= 1) ss[r] += __shfl_xor(ss[r], m, 64);
  }
  if ((lane & 15) == 0) {
#pragma unroll
    for (int r = 0; r < 4; r++) red[wave][quad * 4 + r] = ss[r];
  }
  __syncthreads();
  if (tid < 16) {
    float tot = red[0][tid] + red[1][tid] + red[2][tid] + red[3][tid];
    rnorm[tid] = 1.0f / fmaxf(sqrtf(tot), 1e-12f);
  }
  __syncthreads();
#pragma unroll
  for (int nt = 0; nt < 4; nt++) {
    int o = obase + nt * 16 + col;
#pragma unroll
    for (int r = 0; r < 4; r++) {
      int row = quad * 4 + r;
      tb[o * 18 + row] = f2bf(gv[nt][r]);
      outN[((size_t)(b * TT + t0 + row)) * DIM + o] = f2bf(gv[nt][r] * rnorm[row]);
    }
  }
  __syncthreads();
  {
    int d = tid;
    u32 px[8];
#pragma unroll
    for (int i = 0; i < 8; i++) px[i] = *(const u32*)(tb + d * 18 + i * 2);
    uint4* dst = (uint4*)(outT + ((size_t)(b * 256 + d)) * TT + t0);
    dst[0] = make_uint4(px[0], px[1], px[2], px[3]);
    dst[1] = make_uint4(px[4], px[5], px[6], px[7]);
  }
}

// ---------------- sim = aN . vN^T  (gemm_bt, 128x128 tile, BK=32) ----------
__global__ __launch_bounds__(256) void k_sim(const u16* __restrict__ A,
                                             const u16* __restrict__ Bm,
                                             u16* __restrict__ Cc) {
  __shared__ u16 As[128 * 32], Bs[128 * 32];
  int b = blockIdx.z, m0 = blockIdx.y * 128, n0 = blockIdx.x * 128;
  int tid = threadIdx.x, wave = tid >> 6, lane = tid & 63;
  int col = lane & 15, quad = lane >> 4;
  int wm = (wave >> 1) * 64, wn = (wave & 1) * 64;
  int lrow = lane >> 2, lcol = (lane & 3) * 8;
  const u16* Ab = A + ((size_t)(b * TT + m0)) * DIM;
  const u16* Bb = Bm + ((size_t)(b * TT + n0)) * DIM;
  f32x4 acc[4][4];
  f32x4 zz = {0.f, 0.f, 0.f, 0.f};
#pragma unroll
  for (int i = 0; i < 4; i++)
#pragma unroll
    for (int j = 0; j < 4; j++) acc[i][j] = zz;

  for (int kt = 0; kt < 8; kt++) {
    int k0 = kt * 32;
    if (kt) __syncthreads();
#pragma unroll
    for (int i = 0; i < 2; i++) {
      int rb = wave * 32 + i * 16;
      async16(Ab + ((size_t)(rb + lrow)) * DIM + k0 + lcol, As + rb * 32);
      async16(Bb + ((size_t)(rb + lrow)) * DIM + k0 + lcol, Bs + rb * 32);
    }
    __syncthreads();
    bf16x8 af[4], bfr[4];
#pragma unroll
    for (int mt = 0; mt < 4; mt++) af[mt] = *(const bf16x8*)(As + (wm + mt * 16 + col) * 32 + quad * 8);
#pragma unroll
    for (int nt = 0; nt < 4; nt++) bfr[nt] = *(const bf16x8*)(Bs + (wn + nt * 16 + col) * 32 + quad * 8);
#pragma unroll
    for (int mt = 0; mt < 4; mt++)
#pragma unroll
      for (int nt = 0; nt < 4; nt++)
        acc[mt][nt] = __builtin_amdgcn_mfma_f32_16x16x32_bf16(af[mt], bfr[nt], acc[mt][nt], 0, 0, 0);
  }
#pragma unroll
  for (int mt = 0; mt < 4; mt++)
#pragma unroll
    for (int nt = 0; nt < 4; nt++)
#pragma unroll
      for (int r = 0; r < 4; r++) {
        int row = m0 + wm + mt * 16 + quad * 4 + r;
        int cc = n0 + wn + nt * 16 + col;
        Cc[((size_t)b * TT + row) * TT + cc] = f2bf(acc[mt][nt][r]);
      }
}

// ---------------- row stats: max & sumexp over s (axis -1) -----------------
__global__ __launch_bounds__(256) void k_rowstats(const u16* __restrict__ sim,
                                                  float* __restrict__ rmax,
                                                  float* __restrict__ rsum) {
  int wave = threadIdx.x >> 6, lane = threadIdx.x & 63;
  int row = blockIdx.x * 4 + wave;          // [0, B*T)
  const u32* p = (const u32*)(sim + (size_t)row * TT);
  float xs[24];
  float m = -__builtin_inff();
#pragma unroll
  for (int i = 0; i < 12; i++) {
    u32 v = p[lane + 64 * i];
    float x0 = bf2f((u16)(v & 0xffffu));
    float x1 = bf2f((u16)(v >> 16));
    xs[2 * i] = x0; xs[2 * i + 1] = x1;
    m = fmaxf(m, fmaxf(x0, x1));
  }
#pragma unroll
  for (int s = 1; s < 64; s <<= 1) m = fmaxf(m, __shfl_xor(m, s, 64));
  float l = 0.f;
#pragma unroll
  for (int i = 0; i < 24; i++) l += __expf(xs[i] - m);
#pragma unroll
  for (int s = 1; s < 64; s <<= 1) l += __shfl_xor(l, s, 64);
  if (lane == 0) { rmax[row] = m; rsum[row] = l; }
}

// ---------------- col stats phase 1: partial (max,sumexp) over 128-row chunk
// grid: (TT/256, NCH, B); one thread per column, 4 independent row chains
__global__ __launch_bounds__(256) void k_colstats_part(const u16* __restrict__ sim,
                                                       float* __restrict__ pmax,
                                                       float* __restrict__ psum) {
  int b = blockIdx.z, ch = blockIdx.y;
  int j = blockIdx.x * 256 + threadIdx.x;
  const u16* p = sim + (size_t)b * TT * TT + (size_t)(ch * 128) * TT + j;
  float m[4] = {-__builtin_inff(), -__builtin_inff(), -__builtin_inff(), -__builtin_inff()};
  float l[4] = {0.f, 0.f, 0.f, 0.f};
  for (int i = 0; i < 128; i += 4) {
#pragma unroll
    for (int u = 0; u < 4; u++) {
      float x = bf2f(p[(size_t)(i + u) * TT]);
      float nm = fmaxf(m[u], x);
      l[u] = l[u] * __expf(m[u] - nm) + __expf(x - nm);
      m[u] = nm;
    }
  }
  float M = fmaxf(fmaxf(m[0], m[1]), fmaxf(m[2], m[3]));
  float L = l[0] * __expf(m[0] - M) + l[1] * __expf(m[1] - M) +
            l[2] * __expf(m[2] - M) + l[3] * __expf(m[3] - M);
  size_t o = ((size_t)(b * NCH + ch)) * TT + j;
  pmax[o] = M;
  psum[o] = L;
}

// ---------------- col stats phase 2: combine NCH partials ------------------
__global__ __launch_bounds__(256) void k_colstats_comb(const float* __restrict__ pmax,
                                                       const float* __restrict__ psum,
                                                       float* __restrict__ cmax,
                                                       float* __restrict__ csum) {
  int idx = blockIdx.x * 256 + threadIdx.x;   // [0, B*TT)
  int b = idx / TT, j = idx - b * TT;
  const float* pm = pmax + (size_t)b * NCH * TT + j;
  const float* ps = psum + (size_t)b * NCH * TT + j;
  float M = -__builtin_inff();
#pragma unroll
  for (int ch = 0; ch < NCH; ch++) M = fmaxf(M, pm[(size_t)ch * TT]);
  float L = 0.f;
#pragma unroll
  for (int ch = 0; ch < NCH; ch++) L += ps[(size_t)ch * TT] * __expf(pm[(size_t)ch * TT] - M);
  cmax[idx] = M;
  csum[idx] = L;
}

// ---------------- PV: fused[...] = itp + softmax(sim) @ values -------------
template <int TRANSA>
__global__ __launch_bounds__(256) void k_pv(
    const u16* __restrict__ sim, const u16* __restrict__ Bt,
    const float* __restrict__ stmax, const float* __restrict__ stsum,
    const u16* __restrict__ itp, u16* __restrict__ fused, int dstoff) {
  __shared__ u16 As[64 * 40];         // padded stride 40
  __shared__ u16 Bs[128 * 32];
  __shared__ float sMax[64], sSum[64];
  int b = blockIdx.z, m0 = blockIdx.y * 64, n0 = blockIdx.x * 128;
  int tid = threadIdx.x, wave = tid >> 6, lane = tid & 63;
  int col = lane & 15, quad = lane >> 4;
  int wm = (wave >> 1) * 32, wn = (wave & 1) * 64;
  int lrow = lane >> 2, lcol = (lane & 3) * 8;
  if (tid < 64) {
    sMax[tid] = stmax[b * TT + m0 + tid];
    sSum[tid] = stsum[b * TT + m0 + tid];
  }
  __syncthreads();
  const u16* Bb = Bt + ((size_t)b * 256 + n0) * TT;
  f32x4 acc[2][4];
  f32x4 zz = {0.f, 0.f, 0.f, 0.f};
#pragma unroll
  for (int i = 0; i < 2; i++)
#pragma unroll
    for (int j = 0; j < 4; j++) acc[i][j] = zz;

  for (int kt = 0; kt < 48; kt++) {
    int k0 = kt * 32;
    if (kt) __syncthreads();
#pragma unroll
    for (int i = 0; i < 2; i++) {
      int rb = wave * 32 + i * 16;
      async16(Bb + ((size_t)(rb + lrow)) * TT + k0 + lcol, Bs + rb * 32);
    }
    if (TRANSA == 0) {
      int row = tid >> 2, kp = (tid & 3) * 8;
      uint4 v = *(const uint4*)(sim + ((size_t)(b * TT + m0 + row)) * TT + k0 + kp);
      float mx = sMax[row];
      const u16* pv = (const u16*)&v;
      u32 w[4];
#pragma unroll
      for (int h = 0; h < 4; h++) {
        float e0 = __expf(bf2f(pv[2 * h]) - mx);
        float e1 = __expf(bf2f(pv[2 * h + 1]) - mx);
        w[h] = (u32)f2bf(e0) | ((u32)f2bf(e1) << 16);
      }
      *(uint4*)(As + row * 40 + kp) = make_uint4(w[0], w[1], w[2], w[3]);
    } else {
      int s_r = tid >> 3, tp = (tid & 7) * 8;
      uint4 v = *(const uint4*)(sim + ((size_t)(b * TT + k0 + s_r)) * TT + m0 + tp);
      const u16* pv = (const u16*)&v;
#pragma unroll
      for (int jx = 0; jx < 8; jx++) {
        int j = (jx + (lane & 7)) & 7;  // rotate to spread LDS banks
        float e = __expf(bf2f(pv[j]) - sMax[tp + j]);
        As[(tp + j) * 40 + s_r] = f2bf(e);
      }
    }
    __syncthreads();
    bf16x8 af[2], bfr[4];
#pragma unroll
    for (int mt = 0; mt < 2; mt++) af[mt] = *(const bf16x8*)(As + (wm + mt * 16 + col) * 40 + quad * 8);
#pragma unroll
    for (int nt = 0; nt < 4; nt++) bfr[nt] = *(const bf16x8*)(Bs + (wn + nt * 16 + col) * 32 + quad * 8);
#pragma unroll
    for (int mt = 0; mt < 2; mt++)
#pragma unroll
      for (int nt = 0; nt < 4; nt++)
        acc[mt][nt] = __builtin_amdgcn_mfma_f32_16x16x32_bf16(af[mt], bfr[nt], acc[mt][nt], 0, 0, 0);
  }
#pragma unroll
  for (int mt = 0; mt < 2; mt++)
#pragma unroll
    for (int nt = 0; nt < 4; nt++)
#pragma unroll
      for (int r = 0; r < 4; r++) {
        int row = wm + mt * 16 + quad * 4 + r;
        int t = m0 + row;
        int d = n0 + wn + nt * 16 + col;
        float val = acc[mt][nt][r] / sSum[row] + bf2f(itp[((size_t)(b * TT + t)) * DIM + d]);
        fused[((size_t)(b * TT + t)) * FD + dstoff + d] = f2bf(val);
      }
}

// ---------------- proj: out = gelu(fused @ Wp^T + b), fp32 out -------------
__global__ __launch_bounds__(256) void k_proj(const u16* __restrict__ Am,
                                              const u16* __restrict__ Bw,
                                              const float* __restrict__ bias,
                                              float* __restrict__ out) {
  __shared__ u16 As[128 * 32], Bs[128 * 32];
  int m0 = blockIdx.y * 128, n0 = blockIdx.x * 128;
  int tid = threadIdx.x, wave = tid >> 6, lane = tid & 63;
  int col = lane & 15, quad = lane >> 4;
  int wm = (wave >> 1) * 64, wn = (wave & 1) * 64;
  int lrow = lane >> 2, lcol = (lane & 3) * 8;
  const u16* Ab = Am + (size_t)m0 * FD;
  const u16* Bb = Bw + (size_t)n0 * FD;
  f32x4 acc[4][4];
  f32x4 zz = {0.f, 0.f, 0.f, 0.f};
#pragma unroll
  for (int i = 0; i < 4; i++)
#pragma unroll
    for (int j = 0; j < 4; j++) acc[i][j] = zz;

  for (int kt = 0; kt < 16; kt++) {
    int k0 = kt * 32;
    if (kt) __syncthreads();
#pragma unroll
    for (int i = 0; i < 2; i++) {
      int rb = wave * 32 + i * 16;
      async16(Ab + ((size_t)(rb + lrow)) * FD + k0 + lcol, As + rb * 32);
      async16(Bb + ((size_t)(rb + lrow)) * FD + k0 + lcol, Bs + rb * 32);
    }
    __syncthreads();
    bf16x8 af[4], bfr[4];
#pragma unroll
    for (int mt = 0; mt < 4; mt++) af[mt] = *(const bf16x8*)(As + (wm + mt * 16 + col) * 32 + quad * 8);
#pragma unroll
    for (int nt = 0; nt < 4; nt++) bfr[nt] = *(const bf16x8*)(Bs + (wn + nt * 16 + col) * 32 + quad * 8);
#pragma unroll
    for (int mt = 0; mt < 4; mt++)
#pragma unroll
      for (int nt = 0; nt < 4; nt++)
        acc[mt][nt] = __builtin_amdgcn_mfma_f32_16x16x32_bf16(af[mt], bfr[nt], acc[mt][nt], 0, 0, 0);
  }
#pragma unroll
  for (int nt = 0; nt < 4; nt++) {
    float bia = bias[n0 + wn + nt * 16 + col];
#pragma unroll
    for (int mt = 0; mt < 4; mt++)
#pragma unroll
      for (int r = 0; r < 4; r++) {
        int row = m0 + wm + mt * 16 + quad * 4 + r;
        int cc = n0 + wn + nt * 16 + col;
        out[(size_t)row * FD + cc] = gelu_f(acc[mt][nt][r] + bia);
      }
  }
}

extern "C" void kernel_launch(void* const* d_in, const int* in_sizes, int n_in,
                              void* d_out, int out_size, void* d_ws, size_t ws_size,
                              hipStream_t stream) {
  const float* audio = (const float*)d_in[0];
  const float* video = (const float*)d_in[1];
  const float* a3w = (const float*)d_in[2];
  const float* a3b = (const float*)d_in[3];
  const float* a5w = (const float*)d_in[4];
  const float* a5b = (const float*)d_in[5];
  const float* v3w = (const float*)d_in[6];
  const float* v3b = (const float*)d_in[7];
  const float* v5w = (const float*)d_in[8];
  const float* v5b = (const float*)d_in[9];
  const float* pw  = (const float*)d_in[10];
  const float* pb  = (const float*)d_in[11];
  float* out = (float*)d_out;

  char* ws = (char*)d_ws;
  size_t off = 0;
  auto alloc = [&](size_t bytes) {
    char* p = ws + off;
    off += (bytes + 255) & ~(size_t)255;
    return p;
  };
  size_t szItp = (size_t)BATCH * TT * DIM * 2;
  u16* a_itp = (u16*)alloc(szItp);
  u16* v_itp = (u16*)alloc(szItp);
  u16* aN  = (u16*)alloc(szItp);
  u16* vN  = (u16*)alloc(szItp);
  u16* aMT = (u16*)alloc(szItp);
  u16* vMT = (u16*)alloc(szItp);
  u16* sim = (u16*)alloc((size_t)BATCH * TT * TT * 2);
  float* rmax = (float*)alloc((size_t)BATCH * TT * 4);
  float* rsum = (float*)alloc((size_t)BATCH * TT * 4);
  float* cmax = (float*)alloc((size_t)BATCH * TT * 4);
  float* csum = (float*)alloc((size_t)BATCH * TT * 4);
  float* pmax = (float*)alloc((size_t)BATCH * NCH * TT * 4);
  float* psum = (float*)alloc((size_t)BATCH * NCH * TT * 4);
  u16* fusedb = (u16*)alloc((size_t)BATCH * TT * FD * 2);
  u16* w3a = (u16*)alloc(3 * 128 * 256 * 2);
  u16* w5a = (u16*)alloc(5 * 128 * 256 * 2);
  u16* w3v = (u16*)alloc(3 * 128 * 256 * 2);
  u16* w5v = (u16*)alloc(5 * 128 * 256 * 2);
  u16* wp  = (u16*)alloc(512 * 512 * 2);

  k_prep<<<3072, 256, 0, stream>>>(a3w, a5w, v3w, v5w, pw, w3a, w5a, w3v, w5v, wp);
  k_interp<<<dim3(192, 16), 256, 0, stream>>>(audio, a_itp, TA, (float)((double)TA / TT));
  k_interp<<<dim3(192, 16), 256, 0, stream>>>(video, v_itp, TV, (float)((double)TV / TT));
  k_conv<<<dim3(96, 16), 256, 0, stream>>>(a_itp, w3a, w5a, a3b, a5b, aN, aMT);
  k_conv<<<dim3(96, 16), 256, 0, stream>>>(v_itp, w3v, w5v, v3b, v5b, vN, vMT);
  k_sim<<<dim3(12, 12, 16), 256, 0, stream>>>(aN, vN, sim);
  k_rowstats<<<6144, 256, 0, stream>>>(sim, rmax, rsum);
  k_colstats_part<<<dim3(6, NCH, 16), 256, 0, stream>>>(sim, pmax, psum);
  k_colstats_comb<<<96, 256, 0, stream>>>(pmax, psum, cmax, csum);
  k_pv<0><<<dim3(2, 24, 16), 256, 0, stream>>>(sim, vMT, rmax, rsum, a_itp, fusedb, 0);
  k_pv<1><<<dim3(2, 24, 16), 256, 0, stream>>>(sim, aMT, cmax, csum, v_itp, fusedb, 256);
  k_proj<<<dim3(4, 192), 256, 0, stream>>>(fusedb, wp, pb, out);
}

// Round 3
// 533.688 us; speedup vs baseline: 1.2212x; 1.0430x over previous
//
#include <hip/hip_runtime.h>
#include <math.h>

#define BATCH 16
#define TA 2048
#define TV 1024
#define TT 1536
#define DIM 256
#define FD 512
#define NCH 12   // column-stats row chunks (1536/128)

typedef unsigned short u16;
typedef unsigned int u32;
typedef short bf16x8 __attribute__((ext_vector_type(8)));
typedef float f32x4 __attribute__((ext_vector_type(4)));

__device__ __forceinline__ float bf2f(u16 u) {
  union { u32 i; float f; } v; v.i = ((u32)u) << 16; return v.f;
}
__device__ __forceinline__ u16 f2bf(float f) {
  union { float f; u32 i; } v; v.f = f;
  return (u16)((v.i + 0x7fffu + ((v.i >> 16) & 1u)) >> 16);  // RNE
}
__device__ __forceinline__ float gelu_f(float x) {
  return 0.5f * x * (1.0f + erff(x * 0.70710678118654752440f));
}
// async global->LDS, 16B per lane. LDS dest = wave-uniform base + lane*16.
__device__ __forceinline__ void async16(const u16* g, u16* l) {
  __builtin_amdgcn_global_load_lds((const __attribute__((address_space(1))) void*)g,
                                   (__attribute__((address_space(3))) void*)l, 16, 0, 0);
}

// ---- weight prep: fp32 -> bf16.
// Conv weights permuted to K-ordered async16-ready chunks:
//   W2[kk][unit][8] with kk = tap*8 + c0/32, unit = (o>>4)*64 + q*16 + (o&15),
//   elem j: c = (kk&7)*32 + q*8 + j. Chunk kk = 8 KB contiguous.
__global__ __launch_bounds__(256) void k_prep(
    const float* __restrict__ a3w, const float* __restrict__ a5w,
    const float* __restrict__ v3w, const float* __restrict__ v5w,
    const float* __restrict__ pw,
    u16* __restrict__ w3a, u16* __restrict__ w5a,
    u16* __restrict__ w3v, u16* __restrict__ w5v, u16* __restrict__ wp) {
  int idx = blockIdx.x * 256 + threadIdx.x;
  if (idx < 524288) {
    int e, ktaps;
    const float* src;
    u16* dst;
    if (idx < 98304)       { e = idx;          ktaps = 3; src = a3w; dst = w3a; }
    else if (idx < 262144) { e = idx - 98304;  ktaps = 5; src = a5w; dst = w5a; }
    else if (idx < 360448) { e = idx - 262144; ktaps = 3; src = v3w; dst = w3v; }
    else                   { e = idx - 360448; ktaps = 5; src = v5w; dst = w5v; }
    int kk = e >> 12, r = e & 4095;
    int j = r & 7, unit = r >> 3;
    int fb = unit >> 6, rem = unit & 63;
    int q = rem >> 4, colp = rem & 15;
    int o = fb * 16 + colp;
    int tap = kk >> 3;
    int c = (kk & 7) * 32 + q * 8 + j;
    dst[e] = f2bf(src[(o * 256 + c) * ktaps + tap]);
  } else if (idx < 786432) {               // proj [512][512] straight copy
    int t = idx - 524288;
    wp[t] = f2bf(pw[t]);
  }
}

// ---------------- linear interp to T=1536, output bf16 [B][T][256] ----------
__global__ __launch_bounds__(256) void k_interp(const float* __restrict__ in,
                                                u16* __restrict__ out,
                                                int t_in, float scale) {
  int b = blockIdx.y;
  int i = blockIdx.x * 256 + threadIdx.x;   // [0, TT*32)
  int t = i >> 5, dg = i & 31;              // dg: group of 8 dims
  float src = ((float)t + 0.5f) * scale - 0.5f;
  src = fmaxf(src, 0.0f);
  int i0 = (int)floorf(src);
  if (i0 > t_in - 1) i0 = t_in - 1;
  int i1 = i0 + 1; if (i1 > t_in - 1) i1 = t_in - 1;
  float w = src - (float)i0;
  float om = 1.0f - w;
  const float4* p0 = (const float4*)(in + ((size_t)(b * t_in + i0)) * DIM + dg * 8);
  const float4* p1 = (const float4*)(in + ((size_t)(b * t_in + i1)) * DIM + dg * 8);
  float4 x0a = p0[0], x0b = p0[1], x1a = p1[0], x1b = p1[1];
  u16 r[8];
  r[0] = f2bf(x0a.x * om + x1a.x * w); r[1] = f2bf(x0a.y * om + x1a.y * w);
  r[2] = f2bf(x0a.z * om + x1a.z * w); r[3] = f2bf(x0a.w * om + x1a.w * w);
  r[4] = f2bf(x0b.x * om + x1b.x * w); r[5] = f2bf(x0b.y * om + x1b.y * w);
  r[6] = f2bf(x0b.z * om + x1b.z * w); r[7] = f2bf(x0b.w * om + x1b.w * w);
  u32 w0 = (u32)r[0] | ((u32)r[1] << 16), w1 = (u32)r[2] | ((u32)r[3] << 16);
  u32 w2 = (u32)r[4] | ((u32)r[5] << 16), w3 = (u32)r[6] | ((u32)r[7] << 16);
  *(uint4*)(out + ((size_t)(b * TT + t)) * DIM + dg * 8) = make_uint4(w0, w1, w2, w3);
}

// ---------------- conv GEMM: 64 rows x 256 ch per block, K-streamed weights -
// outM [B][T][256] unnormalized (K-contig for sim), outT [B][256][T],
// nsq [B][T] = sum over 256 ch of gelu^2 (norm applied later in k_sim).
__global__ __launch_bounds__(256) void k_conv(
    const u16* __restrict__ xin,
    const u16* __restrict__ W3, const u16* __restrict__ W5,
    const float* __restrict__ b3, const float* __restrict__ b5,
    u16* __restrict__ outM, u16* __restrict__ outT, float* __restrict__ nsq) {
  __shared__ u16 smem[18432];          // xs: 68 rows x 264 (pad) | tb: 256 x 72
  __shared__ u16 Bs[2 * 4096];         // weight chunk double buffer (2 x 8 KB)
  u16* xs = smem;
  u16* tb = smem;
  int b = blockIdx.y, t0 = blockIdx.x * 64;
  int tid = threadIdx.x, wave = tid >> 6, lane = tid & 63;
  int col = lane & 15, quad = lane >> 4;
  int r0loc = wave * 16;

  // stage 68 input rows (t0-2 .. t0+65), zeros outside [0,T)
  for (int i = tid; i < 68 * 32; i += 256) {
    int row = i >> 5, un = i & 31;
    int t = t0 + row - 2;
    uint4 val = make_uint4(0, 0, 0, 0);
    if (t >= 0 && t < TT) val = *(const uint4*)(xin + ((size_t)(b * TT + t)) * DIM + un * 8);
    *(uint4*)(xs + row * 264 + un * 8) = val;
  }
  // stage weight chunk 0 (k3 kk=0) into buf 0
  {
    const u16* src = W3;
#pragma unroll
    for (int ci = 0; ci < 2; ci++)
      async16(src + wave * 1024 + ci * 512 + lane * 8, Bs + wave * 1024 + ci * 512);
  }

  f32x4 acc3[8], acc5[8];
  f32x4 zz = {0.f, 0.f, 0.f, 0.f};
#pragma unroll
  for (int i = 0; i < 8; i++) { acc3[i] = zz; acc5[i] = zz; }

  for (int s = 0; s < 64; s++) {
    __syncthreads();                   // chunk s staged, xs ready, prev reads done
    if (s < 63) {
      int sn = s + 1;
      const u16* src = (sn < 24) ? (W3 + (size_t)sn * 4096) : (W5 + (size_t)(sn - 24) * 4096);
      u16* dst = Bs + ((sn & 1) * 4096);
#pragma unroll
      for (int ci = 0; ci < 2; ci++)
        async16(src + wave * 1024 + ci * 512 + lane * 8, dst + wave * 1024 + ci * 512);
    }
    int buf = (s & 1) * 4096;
    bool c3 = s < 24;
    int kk = c3 ? s : s - 24;
    int shift = (kk >> 3) - (c3 ? 1 : 2);
    int c0 = (kk & 7) * 32;
    bf16x8 af = *(const bf16x8*)(xs + (r0loc + col + 2 + shift) * 264 + c0 + quad * 8);
    if (c3) {
#pragma unroll
      for (int fb = 0; fb < 8; fb++) {
        bf16x8 bfr = *(const bf16x8*)(Bs + buf + fb * 512 + quad * 128 + col * 8);
        acc3[fb] = __builtin_amdgcn_mfma_f32_16x16x32_bf16(af, bfr, acc3[fb], 0, 0, 0);
      }
    } else {
#pragma unroll
      for (int fb = 0; fb < 8; fb++) {
        bf16x8 bfr = *(const bf16x8*)(Bs + buf + fb * 512 + quad * 128 + col * 8);
        acc5[fb] = __builtin_amdgcn_mfma_f32_16x16x32_bf16(af, bfr, acc5[fb], 0, 0, 0);
      }
    }
  }
  __syncthreads();                     // xs reads done; safe to overlay tb

  // epilogue: bias + gelu + sumsq; write outM + transpose buffer
  float ss[4] = {0.f, 0.f, 0.f, 0.f};
#pragma unroll
  for (int fb = 0; fb < 8; fb++) {
    float bia = b3[fb * 16 + col];
#pragma unroll
    for (int r = 0; r < 4; r++) {
      float g = gelu_f(acc3[fb][r] + bia);
      ss[r] += g * g;
      int tl = r0loc + quad * 4 + r;
      int ch = fb * 16 + col;
      u16 gb = f2bf(g);
      tb[ch * 72 + tl] = gb;
      outM[((size_t)(b * TT + t0 + tl)) * DIM + ch] = gb;
    }
  }
#pragma unroll
  for (int fb = 0; fb < 8; fb++) {
    float bia = b5[fb * 16 + col];
#pragma unroll
    for (int r = 0; r < 4; r++) {
      float g = gelu_f(acc5[fb][r] + bia);
      ss[r] += g * g;
      int tl = r0loc + quad * 4 + r;
      int ch = 128 + fb * 16 + col;
      u16 gb = f2bf(g);
      tb[ch * 72 + tl] = gb;
      outM[((size_t)(b * TT + t0 + tl)) * DIM + ch] = gb;
    }
  }
#pragma unroll
  for (int r = 0; r < 4; r++) {
#pragma unroll
    for (int m = 1; m < 16; m <<= 1) ss[r] += __shfl_xor(ss[r], m, 64);
  }
  if (col == 0) {
#pragma unroll
    for (int r = 0; r < 4; r++)
      nsq[b * TT + t0 + r0loc + quad * 4 + r] = ss[r];
  }
  __syncthreads();
  // outT: thread d writes 64 contiguous t for channel d
  {
    int d = tid;
    uint4* dst = (uint4*)(outT + ((size_t)(b * 256 + d)) * TT + t0);
#pragma unroll
    for (int i = 0; i < 8; i++)
      dst[i] = *(const uint4*)(tb + d * 72 + i * 8);
  }
}

// ---- sim = (aM . vM^T) / (|a||v|)  (gemm_bt, 128x128 tile, BK=32) ---------
__global__ __launch_bounds__(256) void k_sim(const u16* __restrict__ A,
                                             const u16* __restrict__ Bm,
                                             const float* __restrict__ naq,
                                             const float* __restrict__ nvq,
                                             u16* __restrict__ Cc) {
  __shared__ u16 As[128 * 32], Bs[128 * 32];
  __shared__ float sRa[128], sRv[128];
  int b = blockIdx.z, m0 = blockIdx.y * 128, n0 = blockIdx.x * 128;
  int tid = threadIdx.x, wave = tid >> 6, lane = tid & 63;
  int col = lane & 15, quad = lane >> 4;
  int wm = (wave >> 1) * 64, wn = (wave & 1) * 64;
  int lrow = lane >> 2, lcol = (lane & 3) * 8;
  if (tid < 128) sRa[tid] = 1.0f / fmaxf(sqrtf(naq[b * TT + m0 + tid]), 1e-12f);
  else sRv[tid - 128] = 1.0f / fmaxf(sqrtf(nvq[b * TT + n0 + tid - 128]), 1e-12f);
  const u16* Ab = A + ((size_t)(b * TT + m0)) * DIM;
  const u16* Bb = Bm + ((size_t)(b * TT + n0)) * DIM;
  f32x4 acc[4][4];
  f32x4 zz = {0.f, 0.f, 0.f, 0.f};
#pragma unroll
  for (int i = 0; i < 4; i++)
#pragma unroll
    for (int j = 0; j < 4; j++) acc[i][j] = zz;

  for (int kt = 0; kt < 8; kt++) {
    int k0 = kt * 32;
    __syncthreads();
#pragma unroll
    for (int i = 0; i < 2; i++) {
      int rb = wave * 32 + i * 16;
      async16(Ab + ((size_t)(rb + lrow)) * DIM + k0 + lcol, As + rb * 32);
      async16(Bb + ((size_t)(rb + lrow)) * DIM + k0 + lcol, Bs + rb * 32);
    }
    __syncthreads();
    bf16x8 af[4], bfr[4];
#pragma unroll
    for (int mt = 0; mt < 4; mt++) af[mt] = *(const bf16x8*)(As + (wm + mt * 16 + col) * 32 + quad * 8);
#pragma unroll
    for (int nt = 0; nt < 4; nt++) bfr[nt] = *(const bf16x8*)(Bs + (wn + nt * 16 + col) * 32 + quad * 8);
#pragma unroll
    for (int mt = 0; mt < 4; mt++)
#pragma unroll
      for (int nt = 0; nt < 4; nt++)
        acc[mt][nt] = __builtin_amdgcn_mfma_f32_16x16x32_bf16(af[mt], bfr[nt], acc[mt][nt], 0, 0, 0);
  }
#pragma unroll
  for (int mt = 0; mt < 4; mt++)
#pragma unroll
    for (int nt = 0; nt < 4; nt++)
#pragma unroll
      for (int r = 0; r < 4; r++) {
        int rl = wm + mt * 16 + quad * 4 + r;
        int cl = wn + nt * 16 + col;
        float val = acc[mt][nt][r] * sRa[rl] * sRv[cl];
        Cc[((size_t)b * TT + m0 + rl) * TT + n0 + cl] = f2bf(val);
      }
}

// ---------------- row stats: max & sumexp over s (axis -1) -----------------
__global__ __launch_bounds__(256) void k_rowstats(const u16* __restrict__ sim,
                                                  float* __restrict__ rmax,
                                                  float* __restrict__ rsum) {
  int wave = threadIdx.x >> 6, lane = threadIdx.x & 63;
  int row = blockIdx.x * 4 + wave;          // [0, B*T)
  const u32* p = (const u32*)(sim + (size_t)row * TT);
  float xs[24];
  float m = -__builtin_inff();
#pragma unroll
  for (int i = 0; i < 12; i++) {
    u32 v = p[lane + 64 * i];
    float x0 = bf2f((u16)(v & 0xffffu));
    float x1 = bf2f((u16)(v >> 16));
    xs[2 * i] = x0; xs[2 * i + 1] = x1;
    m = fmaxf(m, fmaxf(x0, x1));
  }
#pragma unroll
  for (int s = 1; s < 64; s <<= 1) m = fmaxf(m, __shfl_xor(m, s, 64));
  float l = 0.f;
#pragma unroll
  for (int i = 0; i < 24; i++) l += __expf(xs[i] - m);
#pragma unroll
  for (int s = 1; s < 64; s <<= 1) l += __shfl_xor(l, s, 64);
  if (lane == 0) { rmax[row] = m; rsum[row] = l; }
}

// ---------------- col stats phase 1: partial (max,sumexp) over 128-row chunk
__global__ __launch_bounds__(256) void k_colstats_part(const u16* __restrict__ sim,
                                                       float* __restrict__ pmax,
                                                       float* __restrict__ psum) {
  int b = blockIdx.z, ch = blockIdx.y;
  int j = blockIdx.x * 256 + threadIdx.x;
  const u16* p = sim + (size_t)b * TT * TT + (size_t)(ch * 128) * TT + j;
  float m[4] = {-__builtin_inff(), -__builtin_inff(), -__builtin_inff(), -__builtin_inff()};
  float l[4] = {0.f, 0.f, 0.f, 0.f};
  for (int i = 0; i < 128; i += 4) {
#pragma unroll
    for (int u = 0; u < 4; u++) {
      float x = bf2f(p[(size_t)(i + u) * TT]);
      float nm = fmaxf(m[u], x);
      l[u] = l[u] * __expf(m[u] - nm) + __expf(x - nm);
      m[u] = nm;
    }
  }
  float M = fmaxf(fmaxf(m[0], m[1]), fmaxf(m[2], m[3]));
  float L = l[0] * __expf(m[0] - M) + l[1] * __expf(m[1] - M) +
            l[2] * __expf(m[2] - M) + l[3] * __expf(m[3] - M);
  size_t o = ((size_t)(b * NCH + ch)) * TT + j;
  pmax[o] = M;
  psum[o] = L;
}

// ---------------- col stats phase 2: combine NCH partials ------------------
__global__ __launch_bounds__(256) void k_colstats_comb(const float* __restrict__ pmax,
                                                       const float* __restrict__ psum,
                                                       float* __restrict__ cmax,
                                                       float* __restrict__ csum) {
  int idx = blockIdx.x * 256 + threadIdx.x;   // [0, B*TT)
  int b = idx / TT, j = idx - b * TT;
  const float* pm = pmax + (size_t)b * NCH * TT + j;
  const float* ps = psum + (size_t)b * NCH * TT + j;
  float M = -__builtin_inff();
#pragma unroll
  for (int ch = 0; ch < NCH; ch++) M = fmaxf(M, pm[(size_t)ch * TT]);
  float L = 0.f;
#pragma unroll
  for (int ch = 0; ch < NCH; ch++) L += ps[(size_t)ch * TT] * __expf(pm[(size_t)ch * TT] - M);
  cmax[idx] = M;
  csum[idx] = L;
}

// ---------------- PV: fused[...] = itp + softmax(sim) @ values -------------
template <int TRANSA>
__global__ __launch_bounds__(256) void k_pv(
    const u16* __restrict__ sim, const u16* __restrict__ Bt,
    const float* __restrict__ stmax, const float* __restrict__ stsum,
    const u16* __restrict__ itp, u16* __restrict__ fused, int dstoff) {
  __shared__ u16 As[64 * 40];         // padded stride 40
  __shared__ u16 Bs[128 * 32];
  __shared__ float sMax[64], sSum[64];
  int b = blockIdx.z, m0 = blockIdx.y * 64, n0 = blockIdx.x * 128;
  int tid = threadIdx.x, wave = tid >> 6, lane = tid & 63;
  int col = lane & 15, quad = lane >> 4;
  int wm = (wave >> 1) * 32, wn = (wave & 1) * 64;
  int lrow = lane >> 2, lcol = (lane & 3) * 8;
  if (tid < 64) {
    sMax[tid] = stmax[b * TT + m0 + tid];
    sSum[tid] = stsum[b * TT + m0 + tid];
  }
  __syncthreads();
  const u16* Bb = Bt + ((size_t)b * 256 + n0) * TT;
  f32x4 acc[2][4];
  f32x4 zz = {0.f, 0.f, 0.f, 0.f};
#pragma unroll
  for (int i = 0; i < 2; i++)
#pragma unroll
    for (int j = 0; j < 4; j++) acc[i][j] = zz;

  for (int kt = 0; kt < 48; kt++) {
    int k0 = kt * 32;
    if (kt) __syncthreads();
#pragma unroll
    for (int i = 0; i < 2; i++) {
      int rb = wave * 32 + i * 16;
      async16(Bb + ((size_t)(rb + lrow)) * TT + k0 + lcol, Bs + rb * 32);
    }
    if (TRANSA == 0) {
      int row = tid >> 2, kp = (tid & 3) * 8;
      uint4 v = *(const uint4*)(sim + ((size_t)(b * TT + m0 + row)) * TT + k0 + kp);
      float mx = sMax[row];
      const u16* pv = (const u16*)&v;
      u32 w[4];
#pragma unroll
      for (int h = 0; h < 4; h++) {
        float e0 = __expf(bf2f(pv[2 * h]) - mx);
        float e1 = __expf(bf2f(pv[2 * h + 1]) - mx);
        w[h] = (u32)f2bf(e0) | ((u32)f2bf(e1) << 16);
      }
      *(uint4*)(As + row * 40 + kp) = make_uint4(w[0], w[1], w[2], w[3]);
    } else {
      int s_r = tid >> 3, tp = (tid & 7) * 8;
      uint4 v = *(const uint4*)(sim + ((size_t)(b * TT + k0 + s_r)) * TT + m0 + tp);
      const u16* pv = (const u16*)&v;
#pragma unroll
      for (int jx = 0; jx < 8; jx++) {
        int j = (jx + (lane & 7)) & 7;  // rotate to spread LDS banks
        float e = __expf(bf2f(pv[j]) - sMax[tp + j]);
        As[(tp + j) * 40 + s_r] = f2bf(e);
      }
    }
    __syncthreads();
    bf16x8 af[2], bfr[4];
#pragma unroll
    for (int mt = 0; mt < 2; mt++) af[mt] = *(const bf16x8*)(As + (wm + mt * 16 + col) * 40 + quad * 8);
#pragma unroll
    for (int nt = 0; nt < 4; nt++) bfr[nt] = *(const bf16x8*)(Bs + (wn + nt * 16 + col) * 32 + quad * 8);
#pragma unroll
    for (int mt = 0; mt < 2; mt++)
#pragma unroll
      for (int nt = 0; nt < 4; nt++)
        acc[mt][nt] = __builtin_amdgcn_mfma_f32_16x16x32_bf16(af[mt], bfr[nt], acc[mt][nt], 0, 0, 0);
  }
#pragma unroll
  for (int mt = 0; mt < 2; mt++)
#pragma unroll
    for (int nt = 0; nt < 4; nt++)
#pragma unroll
      for (int r = 0; r < 4; r++) {
        int row = wm + mt * 16 + quad * 4 + r;
        int t = m0 + row;
        int d = n0 + wn + nt * 16 + col;
        float val = acc[mt][nt][r] / sSum[row] + bf2f(itp[((size_t)(b * TT + t)) * DIM + d]);
        fused[((size_t)(b * TT + t)) * FD + dstoff + d] = f2bf(val);
      }
}

// ---------------- proj: out = gelu(fused @ Wp^T + b), fp32 out -------------
__global__ __launch_bounds__(256) void k_proj(const u16* __restrict__ Am,
                                              const u16* __restrict__ Bw,
                                              const float* __restrict__ bias,
                                              float* __restrict__ out) {
  __shared__ u16 As[128 * 32], Bs[128 * 32];
  int m0 = blockIdx.y * 128, n0 = blockIdx.x * 128;
  int tid = threadIdx.x, wave = tid >> 6, lane = tid & 63;
  int col = lane & 15, quad = lane >> 4;
  int wm = (wave >> 1) * 64, wn = (wave & 1) * 64;
  int lrow = lane >> 2, lcol = (lane & 3) * 8;
  const u16* Ab = Am + (size_t)m0 * FD;
  const u16* Bb = Bw + (size_t)n0 * FD;
  f32x4 acc[4][4];
  f32x4 zz = {0.f, 0.f, 0.f, 0.f};
#pragma unroll
  for (int i = 0; i < 4; i++)
#pragma unroll
    for (int j = 0; j < 4; j++) acc[i][j] = zz;

  for (int kt = 0; kt < 16; kt++) {
    int k0 = kt * 32;
    if (kt) __syncthreads();
#pragma unroll
    for (int i = 0; i < 2; i++) {
      int rb = wave * 32 + i * 16;
      async16(Ab + ((size_t)(rb + lrow)) * FD + k0 + lcol, As + rb * 32);
      async16(Bb + ((size_t)(rb + lrow)) * FD + k0 + lcol, Bs + rb * 32);
    }
    __syncthreads();
    bf16x8 af[4], bfr[4];
#pragma unroll
    for (int mt = 0; mt < 4; mt++) af[mt] = *(const bf16x8*)(As + (wm + mt * 16 + col) * 32 + quad * 8);
#pragma unroll
    for (int nt = 0; nt < 4; nt++) bfr[nt] = *(const bf16x8*)(Bs + (wn + nt * 16 + col) * 32 + quad * 8);
#pragma unroll
    for (int mt = 0; mt < 4; mt++)
#pragma unroll
      for (int nt = 0; nt < 4; nt++)
        acc[mt][nt] = __builtin_amdgcn_mfma_f32_16x16x32_bf16(af[mt], bfr[nt], acc[mt][nt], 0, 0, 0);
  }
#pragma unroll
  for (int nt = 0; nt < 4; nt++) {
    float bia = bias[n0 + wn + nt * 16 + col];
#pragma unroll
    for (int mt = 0; mt < 4; mt++)
#pragma unroll
      for (int r = 0; r < 4; r++) {
        int row = m0 + wm + mt * 16 + quad * 4 + r;
        int cc = n0 + wn + nt * 16 + col;
        out[(size_t)row * FD + cc] = gelu_f(acc[mt][nt][r] + bia);
      }
  }
}

extern "C" void kernel_launch(void* const* d_in, const int* in_sizes, int n_in,
                              void* d_out, int out_size, void* d_ws, size_t ws_size,
                              hipStream_t stream) {
  const float* audio = (const float*)d_in[0];
  const float* video = (const float*)d_in[1];
  const float* a3w = (const float*)d_in[2];
  const float* a3b = (const float*)d_in[3];
  const float* a5w = (const float*)d_in[4];
  const float* a5b = (const float*)d_in[5];
  const float* v3w = (const float*)d_in[6];
  const float* v3b = (const float*)d_in[7];
  const float* v5w = (const float*)d_in[8];
  const float* v5b = (const float*)d_in[9];
  const float* pw  = (const float*)d_in[10];
  const float* pb  = (const float*)d_in[11];
  float* out = (float*)d_out;

  char* ws = (char*)d_ws;
  size_t off = 0;
  auto alloc = [&](size_t bytes) {
    char* p = ws + off;
    off += (bytes + 255) & ~(size_t)255;
    return p;
  };
  size_t szItp = (size_t)BATCH * TT * DIM * 2;
  u16* a_itp = (u16*)alloc(szItp);
  u16* v_itp = (u16*)alloc(szItp);
  u16* aM  = (u16*)alloc(szItp);
  u16* vM  = (u16*)alloc(szItp);
  u16* aMT = (u16*)alloc(szItp);
  u16* vMT = (u16*)alloc(szItp);
  u16* sim = (u16*)alloc((size_t)BATCH * TT * TT * 2);
  float* naq = (float*)alloc((size_t)BATCH * TT * 4);
  float* nvq = (float*)alloc((size_t)BATCH * TT * 4);
  float* rmax = (float*)alloc((size_t)BATCH * TT * 4);
  float* rsum = (float*)alloc((size_t)BATCH * TT * 4);
  float* cmax = (float*)alloc((size_t)BATCH * TT * 4);
  float* csum = (float*)alloc((size_t)BATCH * TT * 4);
  float* pmax = (float*)alloc((size_t)BATCH * NCH * TT * 4);
  float* psum = (float*)alloc((size_t)BATCH * NCH * TT * 4);
  u16* fusedb = (u16*)alloc((size_t)BATCH * TT * FD * 2);
  u16* w3a = (u16*)alloc(3 * 128 * 256 * 2);
  u16* w5a = (u16*)alloc(5 * 128 * 256 * 2);
  u16* w3v = (u16*)alloc(3 * 128 * 256 * 2);
  u16* w5v = (u16*)alloc(5 * 128 * 256 * 2);
  u16* wp  = (u16*)alloc(512 * 512 * 2);

  k_prep<<<3072, 256, 0, stream>>>(a3w, a5w, v3w, v5w, pw, w3a, w5a, w3v, w5v, wp);
  k_interp<<<dim3(192, 16), 256, 0, stream>>>(audio, a_itp, TA, (float)((double)TA / TT));
  k_interp<<<dim3(192, 16), 256, 0, stream>>>(video, v_itp, TV, (float)((double)TV / TT));
  k_conv<<<dim3(24, 16), 256, 0, stream>>>(a_itp, w3a, w5a, a3b, a5b, aM, aMT, naq);
  k_conv<<<dim3(24, 16), 256, 0, stream>>>(v_itp, w3v, w5v, v3b, v5b, vM, vMT, nvq);
  k_sim<<<dim3(12, 12, 16), 256, 0, stream>>>(aM, vM, naq, nvq, sim);
  k_rowstats<<<6144, 256, 0, stream>>>(sim, rmax, rsum);
  k_colstats_part<<<dim3(6, NCH, 16), 256, 0, stream>>>(sim, pmax, psum);
  k_colstats_comb<<<96, 256, 0, stream>>>(pmax, psum, cmax, csum);
  k_pv<0><<<dim3(2, 24, 16), 256, 0, stream>>>(sim, vMT, rmax, rsum, a_itp, fusedb, 0);
  k_pv<1><<<dim3(2, 24, 16), 256, 0, stream>>>(sim, aMT, cmax, csum, v_itp, fusedb, 256);
  k_proj<<<dim3(4, 192), 256, 0, stream>>>(fusedb, wp, pb, out);
}

// Round 4
// 462.560 us; speedup vs baseline: 1.4090x; 1.1538x over previous
//
#include <hip/hip_runtime.h>
#include <math.h>

#define BATCH 16
#define TA 2048
#define TV 1024
#define TT 1536
#define DIM 256
#define FD 512

typedef unsigned short u16;
typedef unsigned int u32;
typedef short bf16x8 __attribute__((ext_vector_type(8)));
typedef float f32x4 __attribute__((ext_vector_type(4)));

__device__ __forceinline__ float bf2f(u16 u) {
  union { u32 i; float f; } v; v.i = ((u32)u) << 16; return v.f;
}
__device__ __forceinline__ u16 f2bf(float f) {
  union { float f; u32 i; } v; v.f = f;
  return (u16)((v.i + 0x7fffu + ((v.i >> 16) & 1u)) >> 16);  // RNE
}
__device__ __forceinline__ float gelu_f(float x) {
  return 0.5f * x * (1.0f + erff(x * 0.70710678118654752440f));
}
// async global->LDS, 16B per lane. LDS dest = wave-uniform base + lane*16.
__device__ __forceinline__ void async16(const u16* g, u16* l) {
  __builtin_amdgcn_global_load_lds((const __attribute__((address_space(1))) void*)g,
                                   (__attribute__((address_space(3))) void*)l, 16, 0, 0);
}

// ---- weight prep: fp32 -> bf16.
// Conv weights permuted to K-ordered async16-ready chunks:
//   W2[kk][unit][8] with kk = tap*8 + c0/32, unit = (o>>4)*64 + q*16 + (o&15),
//   elem j: c = (kk&7)*32 + q*8 + j. Chunk kk = 8 KB contiguous.
__global__ __launch_bounds__(256) void k_prep(
    const float* __restrict__ a3w, const float* __restrict__ a5w,
    const float* __restrict__ v3w, const float* __restrict__ v5w,
    const float* __restrict__ pw,
    u16* __restrict__ w3a, u16* __restrict__ w5a,
    u16* __restrict__ w3v, u16* __restrict__ w5v, u16* __restrict__ wp) {
  int idx = blockIdx.x * 256 + threadIdx.x;
  if (idx < 524288) {
    int e, ktaps;
    const float* src;
    u16* dst;
    if (idx < 98304)       { e = idx;          ktaps = 3; src = a3w; dst = w3a; }
    else if (idx < 262144) { e = idx - 98304;  ktaps = 5; src = a5w; dst = w5a; }
    else if (idx < 360448) { e = idx - 262144; ktaps = 3; src = v3w; dst = w3v; }
    else                   { e = idx - 360448; ktaps = 5; src = v5w; dst = w5v; }
    int kk = e >> 12, r = e & 4095;
    int j = r & 7, unit = r >> 3;
    int fb = unit >> 6, rem = unit & 63;
    int q = rem >> 4, colp = rem & 15;
    int o = fb * 16 + colp;
    int tap = kk >> 3;
    int c = (kk & 7) * 32 + q * 8 + j;
    dst[e] = f2bf(src[(o * 256 + c) * ktaps + tap]);
  } else if (idx < 786432) {               // proj [512][512] straight copy
    int t = idx - 524288;
    wp[t] = f2bf(pw[t]);
  }
}

// ---------------- linear interp to T=1536, output bf16 [B][T][256] ----------
__global__ __launch_bounds__(256) void k_interp(const float* __restrict__ in,
                                                u16* __restrict__ out,
                                                int t_in, float scale) {
  int b = blockIdx.y;
  int i = blockIdx.x * 256 + threadIdx.x;   // [0, TT*32)
  int t = i >> 5, dg = i & 31;              // dg: group of 8 dims
  float src = ((float)t + 0.5f) * scale - 0.5f;
  src = fmaxf(src, 0.0f);
  int i0 = (int)floorf(src);
  if (i0 > t_in - 1) i0 = t_in - 1;
  int i1 = i0 + 1; if (i1 > t_in - 1) i1 = t_in - 1;
  float w = src - (float)i0;
  float om = 1.0f - w;
  const float4* p0 = (const float4*)(in + ((size_t)(b * t_in + i0)) * DIM + dg * 8);
  const float4* p1 = (const float4*)(in + ((size_t)(b * t_in + i1)) * DIM + dg * 8);
  float4 x0a = p0[0], x0b = p0[1], x1a = p1[0], x1b = p1[1];
  u16 r[8];
  r[0] = f2bf(x0a.x * om + x1a.x * w); r[1] = f2bf(x0a.y * om + x1a.y * w);
  r[2] = f2bf(x0a.z * om + x1a.z * w); r[3] = f2bf(x0a.w * om + x1a.w * w);
  r[4] = f2bf(x0b.x * om + x1b.x * w); r[5] = f2bf(x0b.y * om + x1b.y * w);
  r[6] = f2bf(x0b.z * om + x1b.z * w); r[7] = f2bf(x0b.w * om + x1b.w * w);
  u32 w0 = (u32)r[0] | ((u32)r[1] << 16), w1 = (u32)r[2] | ((u32)r[3] << 16);
  u32 w2 = (u32)r[4] | ((u32)r[5] << 16), w3 = (u32)r[6] | ((u32)r[7] << 16);
  *(uint4*)(out + ((size_t)(b * TT + t)) * DIM + dg * 8) = make_uint4(w0, w1, w2, w3);
}

// ---------------- conv GEMM: 64 rows x 256 ch per block, K-streamed weights -
__global__ __launch_bounds__(256) void k_conv(
    const u16* __restrict__ xin,
    const u16* __restrict__ W3, const u16* __restrict__ W5,
    const float* __restrict__ b3, const float* __restrict__ b5,
    u16* __restrict__ outM, u16* __restrict__ outT, float* __restrict__ nsq) {
  __shared__ u16 smem[18432];          // xs: 68 rows x 264 (pad) | tb: 256 x 72
  __shared__ u16 Bs[2 * 4096];         // weight chunk double buffer (2 x 8 KB)
  u16* xs = smem;
  u16* tb = smem;
  int b = blockIdx.y, t0 = blockIdx.x * 64;
  int tid = threadIdx.x, wave = tid >> 6, lane = tid & 63;
  int col = lane & 15, quad = lane >> 4;
  int r0loc = wave * 16;

  // stage 68 input rows (t0-2 .. t0+65), zeros outside [0,T)
  for (int i = tid; i < 68 * 32; i += 256) {
    int row = i >> 5, un = i & 31;
    int t = t0 + row - 2;
    uint4 val = make_uint4(0, 0, 0, 0);
    if (t >= 0 && t < TT) val = *(const uint4*)(xin + ((size_t)(b * TT + t)) * DIM + un * 8);
    *(uint4*)(xs + row * 264 + un * 8) = val;
  }
  // stage weight chunk 0 (k3 kk=0) into buf 0
  {
    const u16* src = W3;
#pragma unroll
    for (int ci = 0; ci < 2; ci++)
      async16(src + wave * 1024 + ci * 512 + lane * 8, Bs + wave * 1024 + ci * 512);
  }

  f32x4 acc3[8], acc5[8];
  f32x4 zz = {0.f, 0.f, 0.f, 0.f};
#pragma unroll
  for (int i = 0; i < 8; i++) { acc3[i] = zz; acc5[i] = zz; }

  for (int s = 0; s < 64; s++) {
    __syncthreads();                   // chunk s staged, xs ready, prev reads done
    if (s < 63) {
      int sn = s + 1;
      const u16* src = (sn < 24) ? (W3 + (size_t)sn * 4096) : (W5 + (size_t)(sn - 24) * 4096);
      u16* dst = Bs + ((sn & 1) * 4096);
#pragma unroll
      for (int ci = 0; ci < 2; ci++)
        async16(src + wave * 1024 + ci * 512 + lane * 8, dst + wave * 1024 + ci * 512);
    }
    int buf = (s & 1) * 4096;
    bool c3 = s < 24;
    int kk = c3 ? s : s - 24;
    int shift = (kk >> 3) - (c3 ? 1 : 2);
    int c0 = (kk & 7) * 32;
    bf16x8 af = *(const bf16x8*)(xs + (r0loc + col + 2 + shift) * 264 + c0 + quad * 8);
    if (c3) {
#pragma unroll
      for (int fb = 0; fb < 8; fb++) {
        bf16x8 bfr = *(const bf16x8*)(Bs + buf + fb * 512 + quad * 128 + col * 8);
        acc3[fb] = __builtin_amdgcn_mfma_f32_16x16x32_bf16(af, bfr, acc3[fb], 0, 0, 0);
      }
    } else {
#pragma unroll
      for (int fb = 0; fb < 8; fb++) {
        bf16x8 bfr = *(const bf16x8*)(Bs + buf + fb * 512 + quad * 128 + col * 8);
        acc5[fb] = __builtin_amdgcn_mfma_f32_16x16x32_bf16(af, bfr, acc5[fb], 0, 0, 0);
      }
    }
  }
  __syncthreads();                     // xs reads done; safe to overlay tb

  // epilogue: bias + gelu + sumsq; write outM + transpose buffer
  float ss[4] = {0.f, 0.f, 0.f, 0.f};
#pragma unroll
  for (int fb = 0; fb < 8; fb++) {
    float bia = b3[fb * 16 + col];
#pragma unroll
    for (int r = 0; r < 4; r++) {
      float g = gelu_f(acc3[fb][r] + bia);
      ss[r] += g * g;
      int tl = r0loc + quad * 4 + r;
      int ch = fb * 16 + col;
      u16 gb = f2bf(g);
      tb[ch * 72 + tl] = gb;
      outM[((size_t)(b * TT + t0 + tl)) * DIM + ch] = gb;
    }
  }
#pragma unroll
  for (int fb = 0; fb < 8; fb++) {
    float bia = b5[fb * 16 + col];
#pragma unroll
    for (int r = 0; r < 4; r++) {
      float g = gelu_f(acc5[fb][r] + bia);
      ss[r] += g * g;
      int tl = r0loc + quad * 4 + r;
      int ch = 128 + fb * 16 + col;
      u16 gb = f2bf(g);
      tb[ch * 72 + tl] = gb;
      outM[((size_t)(b * TT + t0 + tl)) * DIM + ch] = gb;
    }
  }
#pragma unroll
  for (int r = 0; r < 4; r++) {
#pragma unroll
    for (int m = 1; m < 16; m <<= 1) ss[r] += __shfl_xor(ss[r], m, 64);
  }
  if (col == 0) {
#pragma unroll
    for (int r = 0; r < 4; r++)
      nsq[b * TT + t0 + r0loc + quad * 4 + r] = ss[r];
  }
  __syncthreads();
  // outT: thread d writes 64 contiguous t for channel d
  {
    int d = tid;
    uint4* dst = (uint4*)(outT + ((size_t)(b * 256 + d)) * TT + t0);
#pragma unroll
    for (int i = 0; i < 8; i++)
      dst[i] = *(const uint4*)(tb + d * 72 + i * 8);
  }
}

// ---------------- zero softmax denominator accumulators --------------------
__global__ __launch_bounds__(256) void k_zero(float* __restrict__ a,
                                              float* __restrict__ b, int n) {
  int i = blockIdx.x * 256 + threadIdx.x;
  if (i < n) { a[i] = 0.f; b[i] = 0.f; }
}

// ---- sim+exp: E = exp((aM.vM^T)/(|a||v|)), write E and E^T (bf16),
//      accumulate rsum (row sums of E) and csum (col sums) via atomics.
//      sim in [-1,1] => exp is numerically safe without max subtraction.
__global__ __launch_bounds__(256) void k_sim(const u16* __restrict__ A,
                                             const u16* __restrict__ Bm,
                                             const float* __restrict__ naq,
                                             const float* __restrict__ nvq,
                                             u16* __restrict__ E,
                                             u16* __restrict__ ET,
                                             float* __restrict__ rsum,
                                             float* __restrict__ csum) {
  __shared__ u16 As[128 * 32], Bs[128 * 32];
  __shared__ float sRa[128], sRv[128];
  int b = blockIdx.z, m0 = blockIdx.y * 128, n0 = blockIdx.x * 128;
  int tid = threadIdx.x, wave = tid >> 6, lane = tid & 63;
  int col = lane & 15, quad = lane >> 4;
  int wm = (wave >> 1) * 64, wn = (wave & 1) * 64;
  int lrow = lane >> 2, lcol = (lane & 3) * 8;
  if (tid < 128) sRa[tid] = 1.0f / fmaxf(sqrtf(naq[b * TT + m0 + tid]), 1e-12f);
  else sRv[tid - 128] = 1.0f / fmaxf(sqrtf(nvq[b * TT + tid - 128 + n0]), 1e-12f);
  const u16* Ab = A + ((size_t)(b * TT + m0)) * DIM;
  const u16* Bb = Bm + ((size_t)(b * TT + n0)) * DIM;
  f32x4 acc[4][4];
  f32x4 zz = {0.f, 0.f, 0.f, 0.f};
#pragma unroll
  for (int i = 0; i < 4; i++)
#pragma unroll
    for (int j = 0; j < 4; j++) acc[i][j] = zz;

  for (int kt = 0; kt < 8; kt++) {
    int k0 = kt * 32;
    __syncthreads();
#pragma unroll
    for (int i = 0; i < 2; i++) {
      int rb = wave * 32 + i * 16;
      async16(Ab + ((size_t)(rb + lrow)) * DIM + k0 + lcol, As + rb * 32);
      async16(Bb + ((size_t)(rb + lrow)) * DIM + k0 + lcol, Bs + rb * 32);
    }
    __syncthreads();
    bf16x8 af[4], bfr[4];
#pragma unroll
    for (int mt = 0; mt < 4; mt++) af[mt] = *(const bf16x8*)(As + (wm + mt * 16 + col) * 32 + quad * 8);
#pragma unroll
    for (int nt = 0; nt < 4; nt++) bfr[nt] = *(const bf16x8*)(Bs + (wn + nt * 16 + col) * 32 + quad * 8);
#pragma unroll
    for (int mt = 0; mt < 4; mt++)
#pragma unroll
      for (int nt = 0; nt < 4; nt++)
        acc[mt][nt] = __builtin_amdgcn_mfma_f32_16x16x32_bf16(af[mt], bfr[nt], acc[mt][nt], 0, 0, 0);
  }

  // epilogue: e = exp(sim); write E row-major + ET transposed (uint2 of 4 rows)
  float rowp[4][4];
#pragma unroll
  for (int mt = 0; mt < 4; mt++)
#pragma unroll
    for (int r = 0; r < 4; r++) rowp[mt][r] = 0.f;

#pragma unroll
  for (int nt = 0; nt < 4; nt++) {
    int cl = wn + nt * 16 + col;
    float rv = sRv[cl];
    float colp = 0.f;
#pragma unroll
    for (int mt = 0; mt < 4; mt++) {
      u16 er[4];
#pragma unroll
      for (int r = 0; r < 4; r++) {
        int rl = wm + mt * 16 + quad * 4 + r;
        float e = __expf(acc[mt][nt][r] * sRa[rl] * rv);
        er[r] = f2bf(e);
        rowp[mt][r] += e;
        colp += e;
        E[((size_t)(b * TT + m0 + rl)) * TT + n0 + cl] = er[r];
      }
      u32 lo = (u32)er[0] | ((u32)er[1] << 16);
      u32 hi = (u32)er[2] | ((u32)er[3] << 16);
      *(uint2*)(ET + ((size_t)(b * TT + n0 + cl)) * TT + m0 + wm + mt * 16 + quad * 4) =
          make_uint2(lo, hi);
    }
    colp += __shfl_xor(colp, 16, 64);
    colp += __shfl_xor(colp, 32, 64);
    if (quad == 0) atomicAdd(&csum[b * TT + n0 + cl], colp);
  }
#pragma unroll
  for (int mt = 0; mt < 4; mt++)
#pragma unroll
    for (int r = 0; r < 4; r++) {
      float v = rowp[mt][r];
      v += __shfl_xor(v, 1, 64); v += __shfl_xor(v, 2, 64);
      v += __shfl_xor(v, 4, 64); v += __shfl_xor(v, 8, 64);
      if (col == 0) atomicAdd(&rsum[b * TT + m0 + wm + mt * 16 + quad * 4 + r], v);
    }
}

// ---------------- PV: fused[...] = itp + (P @ V) / dsum --------------------
// P: [B][T][T] bf16 row-major (E for a_enh, ET for v_enh), k-contiguous.
// Bt: [B][256][T]. Pure m97-style GEMM, 64(m) x 128(n) tile, BK=32.
__global__ __launch_bounds__(256) void k_pv(
    const u16* __restrict__ P, const u16* __restrict__ Bt,
    const float* __restrict__ dsum,
    const u16* __restrict__ itp, u16* __restrict__ fused, int dstoff) {
  __shared__ u16 As[64 * 32];
  __shared__ u16 Bs[128 * 32];
  __shared__ float sSum[64];
  int b = blockIdx.z, m0 = blockIdx.y * 64, n0 = blockIdx.x * 128;
  int tid = threadIdx.x, wave = tid >> 6, lane = tid & 63;
  int col = lane & 15, quad = lane >> 4;
  int wm = (wave >> 1) * 32, wn = (wave & 1) * 64;
  int lrow = lane >> 2, lcol = (lane & 3) * 8;
  if (tid < 64) sSum[tid] = dsum[b * TT + m0 + tid];
  const u16* Ab = P + ((size_t)(b * TT + m0)) * TT;
  const u16* Bb = Bt + ((size_t)(b * 256 + n0)) * TT;
  f32x4 acc[2][4];
  f32x4 zz = {0.f, 0.f, 0.f, 0.f};
#pragma unroll
  for (int i = 0; i < 2; i++)
#pragma unroll
    for (int j = 0; j < 4; j++) acc[i][j] = zz;

  for (int kt = 0; kt < 48; kt++) {
    int k0 = kt * 32;
    __syncthreads();
    async16(Ab + ((size_t)(wave * 16 + lrow)) * TT + k0 + lcol, As + wave * 16 * 32);
#pragma unroll
    for (int i = 0; i < 2; i++) {
      int rb = wave * 32 + i * 16;
      async16(Bb + ((size_t)(rb + lrow)) * TT + k0 + lcol, Bs + rb * 32);
    }
    __syncthreads();
    bf16x8 af[2], bfr[4];
#pragma unroll
    for (int mt = 0; mt < 2; mt++) af[mt] = *(const bf16x8*)(As + (wm + mt * 16 + col) * 32 + quad * 8);
#pragma unroll
    for (int nt = 0; nt < 4; nt++) bfr[nt] = *(const bf16x8*)(Bs + (wn + nt * 16 + col) * 32 + quad * 8);
#pragma unroll
    for (int mt = 0; mt < 2; mt++)
#pragma unroll
      for (int nt = 0; nt < 4; nt++)
        acc[mt][nt] = __builtin_amdgcn_mfma_f32_16x16x32_bf16(af[mt], bfr[nt], acc[mt][nt], 0, 0, 0);
  }
#pragma unroll
  for (int mt = 0; mt < 2; mt++)
#pragma unroll
    for (int nt = 0; nt < 4; nt++)
#pragma unroll
      for (int r = 0; r < 4; r++) {
        int row = wm + mt * 16 + quad * 4 + r;
        int t = m0 + row;
        int d = n0 + wn + nt * 16 + col;
        float val = acc[mt][nt][r] / sSum[row] + bf2f(itp[((size_t)(b * TT + t)) * DIM + d]);
        fused[((size_t)(b * TT + t)) * FD + dstoff + d] = f2bf(val);
      }
}

// ---------------- proj: out = gelu(fused @ Wp^T + b), fp32 out -------------
__global__ __launch_bounds__(256) void k_proj(const u16* __restrict__ Am,
                                              const u16* __restrict__ Bw,
                                              const float* __restrict__ bias,
                                              float* __restrict__ out) {
  __shared__ u16 As[128 * 32], Bs[128 * 32];
  int m0 = blockIdx.y * 128, n0 = blockIdx.x * 128;
  int tid = threadIdx.x, wave = tid >> 6, lane = tid & 63;
  int col = lane & 15, quad = lane >> 4;
  int wm = (wave >> 1) * 64, wn = (wave & 1) * 64;
  int lrow = lane >> 2, lcol = (lane & 3) * 8;
  const u16* Ab = Am + (size_t)m0 * FD;
  const u16* Bb = Bw + (size_t)n0 * FD;
  f32x4 acc[4][4];
  f32x4 zz = {0.f, 0.f, 0.f, 0.f};
#pragma unroll
  for (int i = 0; i < 4; i++)
#pragma unroll
    for (int j = 0; j < 4; j++) acc[i][j] = zz;

  for (int kt = 0; kt < 16; kt++) {
    int k0 = kt * 32;
    __syncthreads();
#pragma unroll
    for (int i = 0; i < 2; i++) {
      int rb = wave * 32 + i * 16;
      async16(Ab + ((size_t)(rb + lrow)) * FD + k0 + lcol, As + rb * 32);
      async16(Bb + ((size_t)(rb + lrow)) * FD + k0 + lcol, Bs + rb * 32);
    }
    __syncthreads();
    bf16x8 af[4], bfr[4];
#pragma unroll
    for (int mt = 0; mt < 4; mt++) af[mt] = *(const bf16x8*)(As + (wm + mt * 16 + col) * 32 + quad * 8);
#pragma unroll
    for (int nt = 0; nt < 4; nt++) bfr[nt] = *(const bf16x8*)(Bs + (wn + nt * 16 + col) * 32 + quad * 8);
#pragma unroll
    for (int mt = 0; mt < 4; mt++)
#pragma unroll
      for (int nt = 0; nt < 4; nt++)
        acc[mt][nt] = __builtin_amdgcn_mfma_f32_16x16x32_bf16(af[mt], bfr[nt], acc[mt][nt], 0, 0, 0);
  }
#pragma unroll
  for (int nt = 0; nt < 4; nt++) {
    float bia = bias[n0 + wn + nt * 16 + col];
#pragma unroll
    for (int mt = 0; mt < 4; mt++)
#pragma unroll
      for (int r = 0; r < 4; r++) {
        int row = m0 + wm + mt * 16 + quad * 4 + r;
        int cc = n0 + wn + nt * 16 + col;
        out[(size_t)row * FD + cc] = gelu_f(acc[mt][nt][r] + bia);
      }
  }
}

extern "C" void kernel_launch(void* const* d_in, const int* in_sizes, int n_in,
                              void* d_out, int out_size, void* d_ws, size_t ws_size,
                              hipStream_t stream) {
  const float* audio = (const float*)d_in[0];
  const float* video = (const float*)d_in[1];
  const float* a3w = (const float*)d_in[2];
  const float* a3b = (const float*)d_in[3];
  const float* a5w = (const float*)d_in[4];
  const float* a5b = (const float*)d_in[5];
  const float* v3w = (const float*)d_in[6];
  const float* v3b = (const float*)d_in[7];
  const float* v5w = (const float*)d_in[8];
  const float* v5b = (const float*)d_in[9];
  const float* pw  = (const float*)d_in[10];
  const float* pb  = (const float*)d_in[11];
  float* out = (float*)d_out;

  char* ws = (char*)d_ws;
  size_t off = 0;
  auto alloc = [&](size_t bytes) {
    char* p = ws + off;
    off += (bytes + 255) & ~(size_t)255;
    return p;
  };
  size_t szItp = (size_t)BATCH * TT * DIM * 2;
  u16* a_itp = (u16*)alloc(szItp);
  u16* v_itp = (u16*)alloc(szItp);
  u16* aM  = (u16*)alloc(szItp);
  u16* vM  = (u16*)alloc(szItp);
  u16* aMT = (u16*)alloc(szItp);
  u16* vMT = (u16*)alloc(szItp);
  u16* E   = (u16*)alloc((size_t)BATCH * TT * TT * 2);
  u16* ET  = (u16*)alloc((size_t)BATCH * TT * TT * 2);
  float* naq = (float*)alloc((size_t)BATCH * TT * 4);
  float* nvq = (float*)alloc((size_t)BATCH * TT * 4);
  float* rsum = (float*)alloc((size_t)BATCH * TT * 4);
  float* csum = (float*)alloc((size_t)BATCH * TT * 4);
  u16* fusedb = (u16*)alloc((size_t)BATCH * TT * FD * 2);
  u16* w3a = (u16*)alloc(3 * 128 * 256 * 2);
  u16* w5a = (u16*)alloc(5 * 128 * 256 * 2);
  u16* w3v = (u16*)alloc(3 * 128 * 256 * 2);
  u16* w5v = (u16*)alloc(5 * 128 * 256 * 2);
  u16* wp  = (u16*)alloc(512 * 512 * 2);

  k_prep<<<3072, 256, 0, stream>>>(a3w, a5w, v3w, v5w, pw, w3a, w5a, w3v, w5v, wp);
  k_interp<<<dim3(192, 16), 256, 0, stream>>>(audio, a_itp, TA, (float)((double)TA / TT));
  k_interp<<<dim3(192, 16), 256, 0, stream>>>(video, v_itp, TV, (float)((double)TV / TT));
  k_conv<<<dim3(24, 16), 256, 0, stream>>>(a_itp, w3a, w5a, a3b, a5b, aM, aMT, naq);
  k_conv<<<dim3(24, 16), 256, 0, stream>>>(v_itp, w3v, w5v, v3b, v5b, vM, vMT, nvq);
  k_zero<<<96, 256, 0, stream>>>(rsum, csum, BATCH * TT);
  k_sim<<<dim3(12, 12, 16), 256, 0, stream>>>(aM, vM, naq, nvq, E, ET, rsum, csum);
  k_pv<<<dim3(2, 24, 16), 256, 0, stream>>>(E, vMT, rsum, a_itp, fusedb, 0);
  k_pv<<<dim3(2, 24, 16), 256, 0, stream>>>(ET, aMT, csum, v_itp, fusedb, 256);
  k_proj<<<dim3(4, 192), 256, 0, stream>>>(fusedb, wp, pb, out);
}

// Round 5
// 381.307 us; speedup vs baseline: 1.7093x; 1.2131x over previous
//
#include <hip/hip_runtime.h>
#include <math.h>

#define BATCH 16
#define TA 2048
#define TV 1024
#define TT 1536
#define DIM 256
#define FD 512

typedef unsigned short u16;
typedef unsigned int u32;
typedef short bf16x8 __attribute__((ext_vector_type(8)));
typedef float f32x4 __attribute__((ext_vector_type(4)));

__device__ __forceinline__ float bf2f(u16 u) {
  union { u32 i; float f; } v; v.i = ((u32)u) << 16; return v.f;
}
__device__ __forceinline__ u16 f2bf(float f) {
  union { float f; u32 i; } v; v.f = f;
  return (u16)((v.i + 0x7fffu + ((v.i >> 16) & 1u)) >> 16);  // RNE
}
__device__ __forceinline__ float gelu_f(float x) {
  return 0.5f * x * (1.0f + erff(x * 0.70710678118654752440f));
}
// async global->LDS, 16B per lane. LDS dest = wave-uniform base + lane*16.
__device__ __forceinline__ void async16(const u16* g, u16* l) {
  __builtin_amdgcn_global_load_lds((const __attribute__((address_space(1))) void*)g,
                                   (__attribute__((address_space(3))) void*)l, 16, 0, 0);
}

// ---- weight prep: fp32 -> bf16.
// Conv weights permuted to K-ordered async16-ready chunks:
//   W[kk][unit][8] with kk = tap*8 + c0/32, unit = (o>>4)*64 + q*16 + (o&15),
//   elem j: c = (kk&7)*32 + q*8 + j. Chunk kk = 8 KB contiguous.
__global__ __launch_bounds__(256) void k_prep(
    const float* __restrict__ a3w, const float* __restrict__ a5w,
    const float* __restrict__ v3w, const float* __restrict__ v5w,
    const float* __restrict__ pw,
    u16* __restrict__ w3a, u16* __restrict__ w5a,
    u16* __restrict__ w3v, u16* __restrict__ w5v, u16* __restrict__ wp) {
  int idx = blockIdx.x * 256 + threadIdx.x;
  if (idx < 524288) {
    int e, ktaps;
    const float* src;
    u16* dst;
    if (idx < 98304)       { e = idx;          ktaps = 3; src = a3w; dst = w3a; }
    else if (idx < 262144) { e = idx - 98304;  ktaps = 5; src = a5w; dst = w5a; }
    else if (idx < 360448) { e = idx - 262144; ktaps = 3; src = v3w; dst = w3v; }
    else                   { e = idx - 360448; ktaps = 5; src = v5w; dst = w5v; }
    int kk = e >> 12, r = e & 4095;
    int j = r & 7, unit = r >> 3;
    int fb = unit >> 6, rem = unit & 63;
    int q = rem >> 4, colp = rem & 15;
    int o = fb * 16 + colp;
    int tap = kk >> 3;
    int c = (kk & 7) * 32 + q * 8 + j;
    dst[e] = f2bf(src[(o * 256 + c) * ktaps + tap]);
  } else if (idx < 786432) {               // proj [512][512] straight copy
    int t = idx - 524288;
    wp[t] = f2bf(pw[t]);
  }
}

// ---------------- linear interp to T=1536, output bf16 [B][T][256] ----------
__global__ __launch_bounds__(256) void k_interp(const float* __restrict__ in,
                                                u16* __restrict__ out,
                                                int t_in, float scale) {
  int b = blockIdx.y;
  int i = blockIdx.x * 256 + threadIdx.x;   // [0, TT*32)
  int t = i >> 5, dg = i & 31;              // dg: group of 8 dims
  float src = ((float)t + 0.5f) * scale - 0.5f;
  src = fmaxf(src, 0.0f);
  int i0 = (int)floorf(src);
  if (i0 > t_in - 1) i0 = t_in - 1;
  int i1 = i0 + 1; if (i1 > t_in - 1) i1 = t_in - 1;
  float w = src - (float)i0;
  float om = 1.0f - w;
  const float4* p0 = (const float4*)(in + ((size_t)(b * t_in + i0)) * DIM + dg * 8);
  const float4* p1 = (const float4*)(in + ((size_t)(b * t_in + i1)) * DIM + dg * 8);
  float4 x0a = p0[0], x0b = p0[1], x1a = p1[0], x1b = p1[1];
  u16 r[8];
  r[0] = f2bf(x0a.x * om + x1a.x * w); r[1] = f2bf(x0a.y * om + x1a.y * w);
  r[2] = f2bf(x0a.z * om + x1a.z * w); r[3] = f2bf(x0a.w * om + x1a.w * w);
  r[4] = f2bf(x0b.x * om + x1b.x * w); r[5] = f2bf(x0b.y * om + x1b.y * w);
  r[6] = f2bf(x0b.z * om + x1b.z * w); r[7] = f2bf(x0b.w * om + x1b.w * w);
  u32 w0 = (u32)r[0] | ((u32)r[1] << 16), w1 = (u32)r[2] | ((u32)r[3] << 16);
  u32 w2 = (u32)r[4] | ((u32)r[5] << 16), w3 = (u32)r[6] | ((u32)r[7] << 16);
  *(uint4*)(out + ((size_t)(b * TT + t)) * DIM + dg * 8) = make_uint4(w0, w1, w2, w3);
}

// ---------------- zero fp32 accumulators -----------------------------------
__global__ __launch_bounds__(256) void k_zero(float* __restrict__ p, int n) {
  int i = blockIdx.x * 256 + threadIdx.x;
  if (i < n) p[i] = 0.f;
}

// ---------------- conv GEMM, fully unrolled, channel-split -----------------
// TAPS=3 -> output channels [0,128), TAPS=5 -> [128,256).
// Per block: 64 t-rows x 128 channels. z selects audio/video.
// Wave w owns channels [w*32, w*32+32) for all 64 rows.
// nsq accumulated atomically (pre-zeroed).
template <int TAPS>
__global__ __launch_bounds__(256) void k_convN(
    const u16* __restrict__ xa, const u16* __restrict__ xv,
    const u16* __restrict__ Wa, const u16* __restrict__ Wv,
    const float* __restrict__ ba, const float* __restrict__ bv,
    u16* __restrict__ outMa, u16* __restrict__ outMv,
    u16* __restrict__ outTa, u16* __restrict__ outTv,
    float* __restrict__ nsqa, float* __restrict__ nsqv) {
  constexpr int S = TAPS * 8;
  constexpr int OFF = (TAPS == 3) ? 1 : 2;
  constexpr int CHB = (TAPS == 3) ? 0 : 128;
  __shared__ __align__(16) u16 xs[68 * 264];   // input rows t0-2..t0+65; tb overlays
  __shared__ __align__(16) u16 Bs[2 * 4096];   // weight chunk double buffer
  u16* tb = xs;                                // [128][72] transpose buffer (epilogue)
  int b = blockIdx.y, t0 = blockIdx.x * 64;
  int isv = blockIdx.z;
  const u16* xin = isv ? xv : xa;
  const u16* W   = isv ? Wv : Wa;
  const float* bias = isv ? bv : ba;
  u16* outM  = isv ? outMv : outMa;
  u16* outT  = isv ? outTv : outTa;
  float* nsq = isv ? nsqv : nsqa;
  int tid = threadIdx.x, wave = tid >> 6, lane = tid & 63;
  int col = lane & 15, quad = lane >> 4;

  // stage 68 input rows (zeros outside [0,T))
  for (int i = tid; i < 68 * 32; i += 256) {
    int row = i >> 5, un = i & 31;
    int t = t0 + row - 2;
    uint4 val = make_uint4(0, 0, 0, 0);
    if (t >= 0 && t < TT) val = *(const uint4*)(xin + ((size_t)(b * TT + t)) * DIM + un * 8);
    *(uint4*)(xs + row * 264 + un * 8) = val;
  }
  // prefetch chunk 0 into buf 0 (each wave stages 1024 elems = 2 x 16B/lane)
  const u16* Wb = W + wave * 1024 + lane * 8;
  u16* BsW = Bs + wave * 1024;
  async16(Wb, BsW);
  async16(Wb + 512, BsW + 512);

  f32x4 acc[4][2];
  f32x4 zz = {0.f, 0.f, 0.f, 0.f};
#pragma unroll
  for (int rt = 0; rt < 4; rt++) { acc[rt][0] = zz; acc[rt][1] = zz; }

  const u16* afp = xs + (col + 2) * 264 + quad * 8;
  const u16* bfp = Bs + wave * 1024 + quad * 128 + col * 8;

#pragma unroll
  for (int s = 0; s < S; s++) {
    __syncthreads();                 // chunk s staged; prev reads of other buf done
    if (s + 1 < S) {
      const u16* src = Wb + (size_t)(s + 1) * 4096;
      u16* dst = Bs + ((s + 1) & 1) * 4096 + wave * 1024;
      async16(src, dst);
      async16(src + 512, dst + 512);
    }
    constexpr int dummy = 0; (void)dummy;
    int shift = (s >> 3) - OFF;      // compile-time after unroll
    int c0 = (s & 7) * 32;
    bf16x8 af[4];
#pragma unroll
    for (int rt = 0; rt < 4; rt++)
      af[rt] = *(const bf16x8*)(afp + (rt * 16 + shift) * 264 + c0);
    bf16x8 bf0 = *(const bf16x8*)(bfp + (s & 1) * 4096);
    bf16x8 bf1 = *(const bf16x8*)(bfp + (s & 1) * 4096 + 512);
#pragma unroll
    for (int rt = 0; rt < 4; rt++) {
      acc[rt][0] = __builtin_amdgcn_mfma_f32_16x16x32_bf16(af[rt], bf0, acc[rt][0], 0, 0, 0);
      acc[rt][1] = __builtin_amdgcn_mfma_f32_16x16x32_bf16(af[rt], bf1, acc[rt][1], 0, 0, 0);
    }
  }
  __syncthreads();                   // xs reads done; safe to overlay tb

  // epilogue: bias + gelu + per-row sumsq (32 ch of this wave) + tb + outM
  float bia0 = bias[wave * 32 + col];
  float bia1 = bias[wave * 32 + 16 + col];
  float ss[4][4];
#pragma unroll
  for (int rt = 0; rt < 4; rt++)
#pragma unroll
    for (int r = 0; r < 4; r++) ss[rt][r] = 0.f;
#pragma unroll
  for (int rt = 0; rt < 4; rt++)
#pragma unroll
    for (int h = 0; h < 2; h++) {
      float bia = h ? bia1 : bia0;
      int chL = wave * 32 + h * 16 + col;
#pragma unroll
      for (int r = 0; r < 4; r++) {
        float g = gelu_f(acc[rt][h][r] + bia);
        ss[rt][r] += g * g;
        int trow = rt * 16 + quad * 4 + r;
        u16 gb = f2bf(g);
        tb[chL * 72 + trow] = gb;
        outM[((size_t)(b * TT + t0 + trow)) * DIM + CHB + chL] = gb;
      }
    }
#pragma unroll
  for (int rt = 0; rt < 4; rt++)
#pragma unroll
    for (int r = 0; r < 4; r++) {
      float v = ss[rt][r];
      v += __shfl_xor(v, 1, 64); v += __shfl_xor(v, 2, 64);
      v += __shfl_xor(v, 4, 64); v += __shfl_xor(v, 8, 64);
      if (col == 0)
        atomicAdd(&nsq[b * TT + t0 + rt * 16 + quad * 4 + r], v);
    }
  __syncthreads();
  // outT: 2 threads per channel write 32 contiguous t each
  {
    int ch = tid >> 1, half = tid & 1;
    uint4* dst = (uint4*)(outT + ((size_t)(b * 256 + CHB + ch)) * TT + t0 + half * 32);
#pragma unroll
    for (int i = 0; i < 4; i++)
      dst[i] = *(const uint4*)(tb + ch * 72 + half * 32 + i * 8);
  }
}

// ---- sim+exp: E = exp((aM.vM^T)/(|a||v|)), write E and E^T (bf16),
//      accumulate rsum (row sums of E) and csum (col sums) via atomics.
//      sim in [-1,1] => exp is numerically safe without max subtraction.
__global__ __launch_bounds__(256) void k_sim(const u16* __restrict__ A,
                                             const u16* __restrict__ Bm,
                                             const float* __restrict__ naq,
                                             const float* __restrict__ nvq,
                                             u16* __restrict__ E,
                                             u16* __restrict__ ET,
                                             float* __restrict__ rsum,
                                             float* __restrict__ csum) {
  __shared__ u16 As[128 * 32], Bs[128 * 32];
  __shared__ float sRa[128], sRv[128];
  int b = blockIdx.z, m0 = blockIdx.y * 128, n0 = blockIdx.x * 128;
  int tid = threadIdx.x, wave = tid >> 6, lane = tid & 63;
  int col = lane & 15, quad = lane >> 4;
  int wm = (wave >> 1) * 64, wn = (wave & 1) * 64;
  int lrow = lane >> 2, lcol = (lane & 3) * 8;
  if (tid < 128) sRa[tid] = 1.0f / fmaxf(sqrtf(naq[b * TT + m0 + tid]), 1e-12f);
  else sRv[tid - 128] = 1.0f / fmaxf(sqrtf(nvq[b * TT + tid - 128 + n0]), 1e-12f);
  const u16* Ab = A + ((size_t)(b * TT + m0)) * DIM;
  const u16* Bb = Bm + ((size_t)(b * TT + n0)) * DIM;
  f32x4 acc[4][4];
  f32x4 zz = {0.f, 0.f, 0.f, 0.f};
#pragma unroll
  for (int i = 0; i < 4; i++)
#pragma unroll
    for (int j = 0; j < 4; j++) acc[i][j] = zz;

  for (int kt = 0; kt < 8; kt++) {
    int k0 = kt * 32;
    __syncthreads();
#pragma unroll
    for (int i = 0; i < 2; i++) {
      int rb = wave * 32 + i * 16;
      async16(Ab + ((size_t)(rb + lrow)) * DIM + k0 + lcol, As + rb * 32);
      async16(Bb + ((size_t)(rb + lrow)) * DIM + k0 + lcol, Bs + rb * 32);
    }
    __syncthreads();
    bf16x8 af[4], bfr[4];
#pragma unroll
    for (int mt = 0; mt < 4; mt++) af[mt] = *(const bf16x8*)(As + (wm + mt * 16 + col) * 32 + quad * 8);
#pragma unroll
    for (int nt = 0; nt < 4; nt++) bfr[nt] = *(const bf16x8*)(Bs + (wn + nt * 16 + col) * 32 + quad * 8);
#pragma unroll
    for (int mt = 0; mt < 4; mt++)
#pragma unroll
      for (int nt = 0; nt < 4; nt++)
        acc[mt][nt] = __builtin_amdgcn_mfma_f32_16x16x32_bf16(af[mt], bfr[nt], acc[mt][nt], 0, 0, 0);
  }

  // epilogue: e = exp(sim); write E row-major + ET transposed (uint2 of 4 rows)
  float rowp[4][4];
#pragma unroll
  for (int mt = 0; mt < 4; mt++)
#pragma unroll
    for (int r = 0; r < 4; r++) rowp[mt][r] = 0.f;

#pragma unroll
  for (int nt = 0; nt < 4; nt++) {
    int cl = wn + nt * 16 + col;
    float rv = sRv[cl];
    float colp = 0.f;
#pragma unroll
    for (int mt = 0; mt < 4; mt++) {
      u16 er[4];
#pragma unroll
      for (int r = 0; r < 4; r++) {
        int rl = wm + mt * 16 + quad * 4 + r;
        float e = __expf(acc[mt][nt][r] * sRa[rl] * rv);
        er[r] = f2bf(e);
        rowp[mt][r] += e;
        colp += e;
        E[((size_t)(b * TT + m0 + rl)) * TT + n0 + cl] = er[r];
      }
      u32 lo = (u32)er[0] | ((u32)er[1] << 16);
      u32 hi = (u32)er[2] | ((u32)er[3] << 16);
      *(uint2*)(ET + ((size_t)(b * TT + n0 + cl)) * TT + m0 + wm + mt * 16 + quad * 4) =
          make_uint2(lo, hi);
    }
    colp += __shfl_xor(colp, 16, 64);
    colp += __shfl_xor(colp, 32, 64);
    if (quad == 0) atomicAdd(&csum[b * TT + n0 + cl], colp);
  }
#pragma unroll
  for (int mt = 0; mt < 4; mt++)
#pragma unroll
    for (int r = 0; r < 4; r++) {
      float v = rowp[mt][r];
      v += __shfl_xor(v, 1, 64); v += __shfl_xor(v, 2, 64);
      v += __shfl_xor(v, 4, 64); v += __shfl_xor(v, 8, 64);
      if (col == 0) atomicAdd(&rsum[b * TT + m0 + wm + mt * 16 + quad * 4 + r], v);
    }
}

// ---------------- PV: fused[...] = itp + (P @ V) / dsum --------------------
// P: [B][T][T] bf16 row-major (E for a_enh, ET for v_enh), k-contiguous.
// Bt: [B][256][T]. Pure m97-style GEMM, 64(m) x 128(n) tile, BK=32.
__global__ __launch_bounds__(256) void k_pv(
    const u16* __restrict__ P, const u16* __restrict__ Bt,
    const float* __restrict__ dsum,
    const u16* __restrict__ itp, u16* __restrict__ fused, int dstoff) {
  __shared__ u16 As[64 * 32];
  __shared__ u16 Bs[128 * 32];
  __shared__ float sSum[64];
  int b = blockIdx.z, m0 = blockIdx.y * 64, n0 = blockIdx.x * 128;
  int tid = threadIdx.x, wave = tid >> 6, lane = tid & 63;
  int col = lane & 15, quad = lane >> 4;
  int wm = (wave >> 1) * 32, wn = (wave & 1) * 64;
  int lrow = lane >> 2, lcol = (lane & 3) * 8;
  if (tid < 64) sSum[tid] = dsum[b * TT + m0 + tid];
  const u16* Ab = P + ((size_t)(b * TT + m0)) * TT;
  const u16* Bb = Bt + ((size_t)(b * 256 + n0)) * TT;
  f32x4 acc[2][4];
  f32x4 zz = {0.f, 0.f, 0.f, 0.f};
#pragma unroll
  for (int i = 0; i < 2; i++)
#pragma unroll
    for (int j = 0; j < 4; j++) acc[i][j] = zz;

  for (int kt = 0; kt < 48; kt++) {
    int k0 = kt * 32;
    __syncthreads();
    async16(Ab + ((size_t)(wave * 16 + lrow)) * TT + k0 + lcol, As + wave * 16 * 32);
#pragma unroll
    for (int i = 0; i < 2; i++) {
      int rb = wave * 32 + i * 16;
      async16(Bb + ((size_t)(rb + lrow)) * TT + k0 + lcol, Bs + rb * 32);
    }
    __syncthreads();
    bf16x8 af[2], bfr[4];
#pragma unroll
    for (int mt = 0; mt < 2; mt++) af[mt] = *(const bf16x8*)(As + (wm + mt * 16 + col) * 32 + quad * 8);
#pragma unroll
    for (int nt = 0; nt < 4; nt++) bfr[nt] = *(const bf16x8*)(Bs + (wn + nt * 16 + col) * 32 + quad * 8);
#pragma unroll
    for (int mt = 0; mt < 2; mt++)
#pragma unroll
      for (int nt = 0; nt < 4; nt++)
        acc[mt][nt] = __builtin_amdgcn_mfma_f32_16x16x32_bf16(af[mt], bfr[nt], acc[mt][nt], 0, 0, 0);
  }
#pragma unroll
  for (int mt = 0; mt < 2; mt++)
#pragma unroll
    for (int nt = 0; nt < 4; nt++)
#pragma unroll
      for (int r = 0; r < 4; r++) {
        int row = wm + mt * 16 + quad * 4 + r;
        int t = m0 + row;
        int d = n0 + wn + nt * 16 + col;
        float val = acc[mt][nt][r] / sSum[row] + bf2f(itp[((size_t)(b * TT + t)) * DIM + d]);
        fused[((size_t)(b * TT + t)) * FD + dstoff + d] = f2bf(val);
      }
}

// ---------------- proj: out = gelu(fused @ Wp^T + b), fp32 out -------------
__global__ __launch_bounds__(256) void k_proj(const u16* __restrict__ Am,
                                              const u16* __restrict__ Bw,
                                              const float* __restrict__ bias,
                                              float* __restrict__ out) {
  __shared__ u16 As[128 * 32], Bs[128 * 32];
  int m0 = blockIdx.y * 128, n0 = blockIdx.x * 128;
  int tid = threadIdx.x, wave = tid >> 6, lane = tid & 63;
  int col = lane & 15, quad = lane >> 4;
  int wm = (wave >> 1) * 64, wn = (wave & 1) * 64;
  int lrow = lane >> 2, lcol = (lane & 3) * 8;
  const u16* Ab = Am + (size_t)m0 * FD;
  const u16* Bb = Bw + (size_t)n0 * FD;
  f32x4 acc[4][4];
  f32x4 zz = {0.f, 0.f, 0.f, 0.f};
#pragma unroll
  for (int i = 0; i < 4; i++)
#pragma unroll
    for (int j = 0; j < 4; j++) acc[i][j] = zz;

  for (int kt = 0; kt < 16; kt++) {
    int k0 = kt * 32;
    __syncthreads();
#pragma unroll
    for (int i = 0; i < 2; i++) {
      int rb = wave * 32 + i * 16;
      async16(Ab + ((size_t)(rb + lrow)) * FD + k0 + lcol, As + rb * 32);
      async16(Bb + ((size_t)(rb + lrow)) * FD + k0 + lcol, Bs + rb * 32);
    }
    __syncthreads();
    bf16x8 af[4], bfr[4];
#pragma unroll
    for (int mt = 0; mt < 4; mt++) af[mt] = *(const bf16x8*)(As + (wm + mt * 16 + col) * 32 + quad * 8);
#pragma unroll
    for (int nt = 0; nt < 4; nt++) bfr[nt] = *(const bf16x8*)(Bs + (wn + nt * 16 + col) * 32 + quad * 8);
#pragma unroll
    for (int mt = 0; mt < 4; mt++)
#pragma unroll
      for (int nt = 0; nt < 4; nt++)
        acc[mt][nt] = __builtin_amdgcn_mfma_f32_16x16x32_bf16(af[mt], bfr[nt], acc[mt][nt], 0, 0, 0);
  }
#pragma unroll
  for (int nt = 0; nt < 4; nt++) {
    float bia = bias[n0 + wn + nt * 16 + col];
#pragma unroll
    for (int mt = 0; mt < 4; mt++)
#pragma unroll
      for (int r = 0; r < 4; r++) {
        int row = m0 + wm + mt * 16 + quad * 4 + r;
        int cc = n0 + wn + nt * 16 + col;
        out[(size_t)row * FD + cc] = gelu_f(acc[mt][nt][r] + bia);
      }
  }
}

extern "C" void kernel_launch(void* const* d_in, const int* in_sizes, int n_in,
                              void* d_out, int out_size, void* d_ws, size_t ws_size,
                              hipStream_t stream) {
  const float* audio = (const float*)d_in[0];
  const float* video = (const float*)d_in[1];
  const float* a3w = (const float*)d_in[2];
  const float* a3b = (const float*)d_in[3];
  const float* a5w = (const float*)d_in[4];
  const float* a5b = (const float*)d_in[5];
  const float* v3w = (const float*)d_in[6];
  const float* v3b = (const float*)d_in[7];
  const float* v5w = (const float*)d_in[8];
  const float* v5b = (const float*)d_in[9];
  const float* pw  = (const float*)d_in[10];
  const float* pb  = (const float*)d_in[11];
  float* out = (float*)d_out;

  char* ws = (char*)d_ws;
  size_t off = 0;
  auto alloc = [&](size_t bytes) {
    char* p = ws + off;
    off += (bytes + 255) & ~(size_t)255;
    return p;
  };
  size_t szItp = (size_t)BATCH * TT * DIM * 2;
  u16* a_itp = (u16*)alloc(szItp);
  u16* v_itp = (u16*)alloc(szItp);
  u16* aM  = (u16*)alloc(szItp);
  u16* vM  = (u16*)alloc(szItp);
  u16* aMT = (u16*)alloc(szItp);
  u16* vMT = (u16*)alloc(szItp);
  u16* E   = (u16*)alloc((size_t)BATCH * TT * TT * 2);
  u16* ET  = (u16*)alloc((size_t)BATCH * TT * TT * 2);
  // NOTE: naq/nvq/rsum/csum must stay adjacent (one k_zero covers all four;
  // each is 16*1536*4 = 98304 B, a multiple of the 256 B alloc granule).
  float* naq = (float*)alloc((size_t)BATCH * TT * 4);
  float* nvq = (float*)alloc((size_t)BATCH * TT * 4);
  float* rsum = (float*)alloc((size_t)BATCH * TT * 4);
  float* csum = (float*)alloc((size_t)BATCH * TT * 4);
  u16* fusedb = (u16*)alloc((size_t)BATCH * TT * FD * 2);
  u16* w3a = (u16*)alloc(3 * 128 * 256 * 2);
  u16* w5a = (u16*)alloc(5 * 128 * 256 * 2);
  u16* w3v = (u16*)alloc(3 * 128 * 256 * 2);
  u16* w5v = (u16*)alloc(5 * 128 * 256 * 2);
  u16* wp  = (u16*)alloc(512 * 512 * 2);

  k_prep<<<3072, 256, 0, stream>>>(a3w, a5w, v3w, v5w, pw, w3a, w5a, w3v, w5v, wp);
  k_interp<<<dim3(192, 16), 256, 0, stream>>>(audio, a_itp, TA, (float)((double)TA / TT));
  k_interp<<<dim3(192, 16), 256, 0, stream>>>(video, v_itp, TV, (float)((double)TV / TT));
  k_zero<<<384, 256, 0, stream>>>(naq, 4 * BATCH * TT);
  k_convN<3><<<dim3(24, 16, 2), 256, 0, stream>>>(a_itp, v_itp, w3a, w3v, a3b, v3b,
                                                  aM, vM, aMT, vMT, naq, nvq);
  k_convN<5><<<dim3(24, 16, 2), 256, 0, stream>>>(a_itp, v_itp, w5a, w5v, a5b, v5b,
                                                  aM, vM, aMT, vMT, naq, nvq);
  k_sim<<<dim3(12, 12, 16), 256, 0, stream>>>(aM, vM, naq, nvq, E, ET, rsum, csum);
  k_pv<<<dim3(2, 24, 16), 256, 0, stream>>>(E, vMT, rsum, a_itp, fusedb, 0);
  k_pv<<<dim3(2, 24, 16), 256, 0, stream>>>(ET, aMT, csum, v_itp, fusedb, 256);
  k_proj<<<dim3(4, 192), 256, 0, stream>>>(fusedb, wp, pb, out);
}